// Round 4
// baseline (669.144 us; speedup 1.0000x reference)
//
#include <hip/hip_runtime.h>
#include <hip/hip_bf16.h>

// GCN encoder: conv1(512->256) -> BN -> ReLU -> conv2(256->128) -> BN
// R10: phased aggregation, latency-fixed. R9 post-mortem: bucket phasing cut
// FETCH 358->150MB (theory confirmed) but dur rose to 172us -- 208 tiny runs
// per wave each with a serial readlane->col->dis->gather chain. Fix: counting
// sort key reordered to (chunk=16-node wave tile, src_bucket, node_in_chunk),
// so each wave's bucket-b edges are ONE contiguous col segment (~32 edges):
// one coalesced col load + one dis gather per BUCKET (not per run), then
// readlane-broadcast (src,w) from registers and 2-deep independent H gathers.
// Run bounds live in 4 boundary VGPRs (lanes 0..63 = bptr values), selected
// per bucket-group statically (no dynamic reg indexing). NPB 400/NDB 125
// aligns chunks exactly: 3125 chunks, grid 782 blocks, launch_bounds(256,4)
// -> all resident; per-bucket __syncthreads kept (it produced the 150MB).
// Kept: two-pass LDS counting-sort CSR build, MFMA GEMMs, BN1+ReLU fused in
// gemm2 staging, part[] aliasing H1.

#define NN 50000
#define NE 1600000
#define DIN 512
#define D1 256
#define D2 128
#define EPSV 1e-5f
#define NBUCK 16     // src buckets; 4 bits in packed word (bits 25-28)
#define BSZ 3125     // src nodes per bucket (16*3125 = 50000)
#define NDB 125      // dst buckets (CSR build blocks)
#define NPB 400      // nodes per dst bucket (125*400 = 50000 exact)
#define CAP 16384    // part capacity per dst bucket (mean 12800, >31 sigma)
#define KN 16        // nodes per chunk (= per wave)
#define NCHUNK (NN / KN)                    // 3125
#define AGG_GRID ((NCHUNK + 3) / 4)         // 782 blocks, all resident

typedef __attribute__((ext_vector_type(8))) short bf16x8_t;
typedef __attribute__((ext_vector_type(4))) float f32x4_t;

__device__ __forceinline__ float bf2f(unsigned short u) {
  return __uint_as_float(((unsigned int)u) << 16);
}
__device__ __forceinline__ unsigned short f2bf(float f) {
  unsigned int u = __float_as_uint(f);
  u += 0x7fffu + ((u >> 16) & 1u);   // RNE
  return (unsigned short)(u >> 16);
}
__device__ __forceinline__ unsigned int pk2(float a, float b) {
  __hip_bfloat162 h = __float22bfloat162_rn(make_float2(a, b));
  union { __hip_bfloat162 h; unsigned int u; } c;
  c.h = h;
  return c.u;
}

// ---------- CSR build: two-pass LDS counting sort ----------
__global__ void k_zero(int* __restrict__ gcursor, float* __restrict__ stats) {
  int i = blockIdx.x * 256 + threadIdx.x;
  if (i < NDB) gcursor[i] = 0;
  if (i < (D1 * 2 + D2 * 2)) stats[i] = 0.0f;
}

// Pass A: partition edges into 125 dst-range buckets (fixed CAP stride).
// packed word: src (16b) | dst_local (9b, <<16) | src_bucket (4b, <<25)
__global__ __launch_bounds__(256) void k_part(const int* __restrict__ src,
                                              const int* __restrict__ dst,
                                              int* __restrict__ gcursor,
                                              unsigned int* __restrict__ part) {
  __shared__ int hist[NDB];
  __shared__ int curs[NDB];
  const int t = threadIdx.x;
  const int EB = NE / 256;  // 6250 edges per block
  const int e0 = blockIdx.x * EB;
  if (t < NDB) hist[t] = 0;
  __syncthreads();
  for (int i = t; i < EB; i += 256) {
    int d = dst[e0 + i];
    atomicAdd(&hist[d / NPB], 1);
  }
  __syncthreads();
  if (t < NDB) {
    int c = hist[t];
    curs[t] = (c > 0) ? atomicAdd(&gcursor[t], c) : 0;
  }
  __syncthreads();
  for (int i = t; i < EB; i += 256) {
    int s = src[e0 + i];
    int d = dst[e0 + i];
    int b = d / NPB;
    int dl = d - b * NPB;
    int sb = (unsigned)s / BSZ;
    unsigned int w = (unsigned)s | ((unsigned)dl << 16) | ((unsigned)sb << 25);
    int pos = atomicAdd(&curs[b], 1);
    if (pos < CAP) part[(size_t)b * CAP + pos] = w;
  }
}

// exclusive prefix over 125 bucket totals -> ebase
__global__ void k_bscan(const int* __restrict__ gcursor, int* __restrict__ ebase) {
  __shared__ int s[128];
  int t = threadIdx.x;  // blockDim = 128
  int v = (t < NDB) ? gcursor[t] : 0;
  s[t] = v;
  __syncthreads();
  for (int off = 1; off < 128; off <<= 1) {
    int a = (t >= off) ? s[t - off] : 0;
    __syncthreads();
    s[t] += a;
    __syncthreads();
  }
  if (t < NDB) ebase[t] = s[t] - v;
  if (t == NDB - 1) ebase[NDB] = s[t];
}

// Pass B: per dst-bucket LDS counting sort by (chunk_local, src_bucket,
// node_in_chunk). Emits bptr[chunk*256 + bucket*16 + ni], dis, and col
// (per-(chunk,bucket) contiguous segments).
__global__ __launch_bounds__(256) void k_build(const unsigned int* __restrict__ part,
                                               const int* __restrict__ gcursor,
                                               const int* __restrict__ ebase,
                                               int* __restrict__ bptr,
                                               float* __restrict__ dis,
                                               int* __restrict__ col) {
  const int NC = NPB * NBUCK;  // 6400 counters
  __shared__ int cnt[NC];
  __shared__ int tsum[256];
  const int b = blockIdx.x, t = threadIdx.x;
  int m = gcursor[b];
  if (m > CAP) m = CAP;
  const int base = ebase[b];
  const unsigned int* my = part + (size_t)b * CAP;
  for (int i = t; i < NC; i += 256) cnt[i] = 0;
  __syncthreads();
  for (int i = t; i < m; i += 256) {
    unsigned int w = my[i];
    int dl = (w >> 16) & 0x1ff;
    int sb = w >> 25;
    atomicAdd(&cnt[(dl >> 4) * 256 + sb * 16 + (dl & 15)], 1);
  }
  __syncthreads();
  // degree -> dis (read counts before scan overwrites)
  for (int dl = t; dl < NPB; dl += 256) {
    int cl = dl >> 4, ni = dl & 15;
    int deg = 0;
#pragma unroll
    for (int bk = 0; bk < NBUCK; bk++) deg += cnt[cl * 256 + bk * 16 + ni];
    dis[b * NPB + dl] = rsqrtf((float)(deg + 1));  // +1 self loop
  }
  __syncthreads();
  // exclusive scan of cnt[0..NC)
  const int CHK = NC / 256;  // 25
  int i0 = t * CHK;
  int sum = 0;
  for (int i = 0; i < CHK; i++) sum += cnt[i0 + i];
  tsum[t] = sum;
  __syncthreads();
  for (int off = 1; off < 256; off <<= 1) {
    int a = (t >= off) ? tsum[t - off] : 0;
    __syncthreads();
    tsum[t] += a;
    __syncthreads();
  }
  int run = tsum[t] - sum;
  for (int i = 0; i < CHK; i++) {
    int idx = i0 + i;
    int c = cnt[idx];
    cnt[idx] = run;
    run += c;
  }
  __syncthreads();
  // bptr from scan values
  for (int i = t; i < NC; i += 256) {
    int cl = i >> 8;
    bptr[(size_t)(b * (NPB / KN) + cl) * 256 + (i & 255)] = base + cnt[i];
  }
  if (b == NDB - 1 && t == 0) bptr[(size_t)NCHUNK * 256] = base + m;
  __syncthreads();
  // scatter (cnt now serves as cursors)
  for (int i = t; i < m; i += 256) {
    unsigned int w = my[i];
    int dl = (w >> 16) & 0x1ff;
    int sb = w >> 25;
    int pos = atomicAdd(&cnt[(dl >> 4) * 256 + sb * 16 + (dl & 15)], 1);
    col[base + pos] = w & 0xffff;
  }
}

// ---------- weight prep: W [KxN] fp32 -> Wt [NxK] bf16 ----------
__global__ void k_prep_w(const float* __restrict__ W1, const float* __restrict__ W2,
                         unsigned short* __restrict__ W1t, unsigned short* __restrict__ W2t) {
  int i = blockIdx.x * 256 + threadIdx.x;
  if (i < DIN * D1) {  // W1t[n*DIN + k] = W1[k*D1 + n]
    int n = i / DIN, k = i - n * DIN;
    W1t[i] = f2bf(W1[(size_t)k * D1 + n]);
  } else {
    int j = i - DIN * D1;  // W2t[n*D1 + k] = W2[k*D2 + n]
    int n = j / D1, k = j - n * D1;
    W2t[j] = f2bf(W2[(size_t)k * D2 + n]);
  }
}

// ---------- GEMM1: H1[M x 256] = x[M x 512] @ W1t[256 x 512]^T ----------
__global__ __launch_bounds__(512) void k_gemm1(const float* __restrict__ A,
                                               const unsigned short* __restrict__ Bt,
                                               unsigned short* __restrict__ C, int M) {
  __shared__ unsigned short As[128 * 64];
  __shared__ unsigned short Bs[256 * 64];
  const int t = threadIdx.x;
  const int wave = t >> 6, lane = t & 63;
  const int m0 = blockIdx.x * 128;
  const int wm = (wave & 1) * 64, wn = (wave >> 1) * 64;  // 2x4 wave grid
  const int l8 = lane >> 3;
  const int lbs = (lane & 7) ^ l8;
  const int row_c = lane & 15, quad = lane >> 4;

  f32x4_t acc[4][4];
#pragma unroll
  for (int i = 0; i < 4; i++)
#pragma unroll
    for (int j = 0; j < 4; j++) acc[i][j] = (f32x4_t){0.f, 0.f, 0.f, 0.f};

  for (int k0 = 0; k0 < DIN; k0 += 64) {
#pragma unroll
    for (int j = 0; j < 4; j++) {
      int chunk = wave * 4 + j;
      int row = chunk * 8 + l8;
      const unsigned short* g = Bt + (size_t)row * DIN + k0 + lbs * 8;
      __builtin_amdgcn_global_load_lds(
          (const __attribute__((address_space(1))) unsigned int*)g,
          (__attribute__((address_space(3))) unsigned int*)(Bs + chunk * 512), 16, 0, 0);
    }
#pragma unroll
    for (int i = 0; i < 2; i++) {
      int bid = i * 512 + t;
      int row = bid >> 3, pb = bid & 7;
      int lb = pb ^ (row & 7);
      int gm = m0 + row;
      if (gm >= M) gm = M - 1;
      const float4* s = (const float4*)(A + (size_t)gm * DIN + k0 + lb * 8);
      float4 v0 = s[0], v1 = s[1];
      uint4 o;
      o.x = pk2(v0.x, v0.y);
      o.y = pk2(v0.z, v0.w);
      o.z = pk2(v1.x, v1.y);
      o.w = pk2(v1.z, v1.w);
      *(uint4*)(As + row * 64 + pb * 8) = o;
    }
    __syncthreads();
#pragma unroll
    for (int ki = 0; ki < 2; ki++) {
      bf16x8_t af[4], bfr[4];
      int kb = ki * 4 + quad;
#pragma unroll
      for (int i = 0; i < 4; i++) {
        int ar = wm + i * 16 + row_c;
        af[i] = *(const bf16x8_t*)(As + ar * 64 + ((kb ^ (ar & 7)) * 8));
        int br = wn + i * 16 + row_c;
        bfr[i] = *(const bf16x8_t*)(Bs + br * 64 + ((kb ^ (br & 7)) * 8));
      }
#pragma unroll
      for (int i = 0; i < 4; i++)
#pragma unroll
        for (int j = 0; j < 4; j++)
          acc[i][j] = __builtin_amdgcn_mfma_f32_16x16x32_bf16(af[i], bfr[j], acc[i][j], 0, 0, 0);
    }
    __syncthreads();
  }
#pragma unroll
  for (int i = 0; i < 4; i++) {
#pragma unroll
    for (int j = 0; j < 4; j++) {
      int colv = wn + j * 16 + row_c;
#pragma unroll
      for (int r = 0; r < 4; r++) {
        int gm = m0 + wm + i * 16 + quad * 4 + r;
        if (gm < M) C[(size_t)gm * D1 + colv] = f2bf(acc[i][j][r]);
      }
    }
  }
}

// per-column BN1 scale/shift from stats
__global__ void k_finalize1(const float* __restrict__ stats, const float* __restrict__ gamma,
                            const float* __restrict__ beta, float* __restrict__ sc1,
                            float* __restrict__ sh1) {
  int c = threadIdx.x;  // 256
  float mean = stats[c] * (1.0f / NN);
  float var = stats[D1 + c] * (1.0f / NN) - mean * mean;
  float sc = gamma[c] * rsqrtf(var + EPSV);
  sc1[c] = sc;
  sh1[c] = beta[c] - mean * sc;
}

// ---------- GEMM2: H2[M x 128] = relu(BN(A1))[M x 256] @ W2t[128 x 256]^T ----------
__global__ __launch_bounds__(256) void k_gemm2(const unsigned short* __restrict__ A,
                                               const float* __restrict__ sc1,
                                               const float* __restrict__ sh1,
                                               const unsigned short* __restrict__ Bt,
                                               unsigned short* __restrict__ C, int M) {
  __shared__ unsigned short As[128 * 64];
  __shared__ unsigned short Bs[128 * 64];
  const int t = threadIdx.x;
  const int wave = t >> 6, lane = t & 63;
  const int m0 = blockIdx.x * 128;
  const int wm = (wave >> 1) * 64, wn = (wave & 1) * 64;
  const int l8 = lane >> 3;
  const int lbs = (lane & 7) ^ l8;
  const int row_c = lane & 15, quad = lane >> 4;

  f32x4_t acc[4][4];
#pragma unroll
  for (int i = 0; i < 4; i++)
#pragma unroll
    for (int j = 0; j < 4; j++) acc[i][j] = (f32x4_t){0.f, 0.f, 0.f, 0.f};

  for (int k0 = 0; k0 < D1; k0 += 64) {
#pragma unroll
    for (int j = 0; j < 4; j++) {
      int chunk = wave * 4 + j;
      int row = chunk * 8 + l8;
      const unsigned short* g = Bt + (size_t)row * D1 + k0 + lbs * 8;
      __builtin_amdgcn_global_load_lds(
          (const __attribute__((address_space(1))) unsigned int*)g,
          (__attribute__((address_space(3))) unsigned int*)(Bs + chunk * 512), 16, 0, 0);
    }
#pragma unroll
    for (int i = 0; i < 4; i++) {
      int bid = i * 256 + t;
      int row = bid >> 3, pb = bid & 7;
      int lb = pb ^ (row & 7);
      int gm = m0 + row;
      if (gm >= M) gm = M - 1;
      int colb = k0 + lb * 8;
      uint4 raw = *(const uint4*)(A + (size_t)gm * D1 + colb);
      float4 scA = *(const float4*)(sc1 + colb);
      float4 scB = *(const float4*)(sc1 + colb + 4);
      float4 shA = *(const float4*)(sh1 + colb);
      float4 shB = *(const float4*)(sh1 + colb + 4);
      float f0 = fmaxf(fmaf(bf2f((unsigned short)(raw.x & 0xffff)), scA.x, shA.x), 0.f);
      float f1 = fmaxf(fmaf(bf2f((unsigned short)(raw.x >> 16)),    scA.y, shA.y), 0.f);
      float f2 = fmaxf(fmaf(bf2f((unsigned short)(raw.y & 0xffff)), scA.z, shA.z), 0.f);
      float f3 = fmaxf(fmaf(bf2f((unsigned short)(raw.y >> 16)),    scA.w, shA.w), 0.f);
      float f4 = fmaxf(fmaf(bf2f((unsigned short)(raw.z & 0xffff)), scB.x, shB.x), 0.f);
      float f5 = fmaxf(fmaf(bf2f((unsigned short)(raw.z >> 16)),    scB.y, shB.y), 0.f);
      float f6 = fmaxf(fmaf(bf2f((unsigned short)(raw.w & 0xffff)), scB.z, shB.z), 0.f);
      float f7 = fmaxf(fmaf(bf2f((unsigned short)(raw.w >> 16)),    scB.w, shB.w), 0.f);
      uint4 o;
      o.x = pk2(f0, f1);
      o.y = pk2(f2, f3);
      o.z = pk2(f4, f5);
      o.w = pk2(f6, f7);
      *(uint4*)(As + row * 64 + pb * 8) = o;
    }
    __syncthreads();
#pragma unroll
    for (int ki = 0; ki < 2; ki++) {
      bf16x8_t af[4], bfr[4];
      int kb = ki * 4 + quad;
#pragma unroll
      for (int i = 0; i < 4; i++) {
        int ar = wm + i * 16 + row_c;
        af[i] = *(const bf16x8_t*)(As + ar * 64 + ((kb ^ (ar & 7)) * 8));
        int br = wn + i * 16 + row_c;
        bfr[i] = *(const bf16x8_t*)(Bs + br * 64 + ((kb ^ (br & 7)) * 8));
      }
#pragma unroll
      for (int i = 0; i < 4; i++)
#pragma unroll
        for (int j = 0; j < 4; j++)
          acc[i][j] = __builtin_amdgcn_mfma_f32_16x16x32_bf16(af[i], bfr[j], acc[i][j], 0, 0, 0);
    }
    __syncthreads();
  }
#pragma unroll
  for (int i = 0; i < 4; i++) {
#pragma unroll
    for (int j = 0; j < 4; j++) {
      int colv = wn + j * 16 + row_c;
      if (colv < D2) {
#pragma unroll
        for (int r = 0; r < 4; r++) {
          int gm = m0 + wm + i * 16 + quad * 4 + r;
          if (gm < M) C[(size_t)gm * D2 + colv] = f2bf(acc[i][j][r]);
        }
      }
    }
  }
}

// ---------- phased aggregation helpers ----------
// One bucket for agg1: contiguous segment [S,E) covers all KN runs. One
// coalesced col load + one dis gather; per-run readlane broadcasts; 2-deep
// H gathers. Trailing __syncthreads keeps the block's waves in phase.
__device__ __forceinline__ void agg_bucket1(
    bool active, int lane, int bndv, int idx0, int endv,
    const unsigned short* __restrict__ H, const int* __restrict__ col,
    const float* __restrict__ dis,
    float (&a0)[KN], float (&a1)[KN], float (&a2)[KN], float (&a3)[KN]) {
  if (active) {
    int S = __builtin_amdgcn_readlane(bndv, idx0);
    int E = endv;
    int len = E - S;
    if (len > 0 && len <= 64) {
      int li = (lane < len) ? lane : (len - 1);
      int cw = col[S + li];
      int dwu = __float_as_int(dis[cw]);
#pragma unroll
      for (int j = 0; j < KN; j++) {
        int sj = (j == 0) ? S : __builtin_amdgcn_readlane(bndv, idx0 + j);
        int ej = (j == KN - 1) ? E : __builtin_amdgcn_readlane(bndv, idx0 + j + 1);
        int k = sj;
        for (; k + 2 <= ej; k += 2) {
          int s0 = __builtin_amdgcn_readlane(cw, k - S);
          int s1 = __builtin_amdgcn_readlane(cw, k + 1 - S);
          float w0 = __int_as_float(__builtin_amdgcn_readlane(dwu, k - S));
          float w1 = __int_as_float(__builtin_amdgcn_readlane(dwu, k + 1 - S));
          ushort4 u0 = ((const ushort4*)(H + (size_t)s0 * D1))[lane];
          ushort4 u1 = ((const ushort4*)(H + (size_t)s1 * D1))[lane];
          a0[j] += w0 * bf2f(u0.x) + w1 * bf2f(u1.x);
          a1[j] += w0 * bf2f(u0.y) + w1 * bf2f(u1.y);
          a2[j] += w0 * bf2f(u0.z) + w1 * bf2f(u1.z);
          a3[j] += w0 * bf2f(u0.w) + w1 * bf2f(u1.w);
        }
        if (k < ej) {
          int s0 = __builtin_amdgcn_readlane(cw, k - S);
          float w0 = __int_as_float(__builtin_amdgcn_readlane(dwu, k - S));
          ushort4 u0 = ((const ushort4*)(H + (size_t)s0 * D1))[lane];
          a0[j] += w0 * bf2f(u0.x);
          a1[j] += w0 * bf2f(u0.y);
          a2[j] += w0 * bf2f(u0.z);
          a3[j] += w0 * bf2f(u0.w);
        }
      }
    } else if (len > 64) {  // statistically ~never (mean 32, 64 = +5.7 sigma)
#pragma unroll
      for (int j = 0; j < KN; j++) {
        int sj = (j == 0) ? S : __builtin_amdgcn_readlane(bndv, idx0 + j);
        int ej = (j == KN - 1) ? E : __builtin_amdgcn_readlane(bndv, idx0 + j + 1);
        for (int k = sj; k < ej; k++) {
          int sv = col[k];
          float w = dis[sv];
          ushort4 u = ((const ushort4*)(H + (size_t)sv * D1))[lane];
          a0[j] += w * bf2f(u.x);
          a1[j] += w * bf2f(u.y);
          a2[j] += w * bf2f(u.z);
          a3[j] += w * bf2f(u.w);
        }
      }
    }
  }
  __syncthreads();
}

__device__ __forceinline__ void agg_bucket2(
    bool active, int lane, int bndv, int idx0, int endv,
    const unsigned short* __restrict__ H, const int* __restrict__ col,
    const float* __restrict__ dis, float (&a0)[KN], float (&a1)[KN]) {
  if (active) {
    int S = __builtin_amdgcn_readlane(bndv, idx0);
    int E = endv;
    int len = E - S;
    if (len > 0 && len <= 64) {
      int li = (lane < len) ? lane : (len - 1);
      int cw = col[S + li];
      int dwu = __float_as_int(dis[cw]);
#pragma unroll
      for (int j = 0; j < KN; j++) {
        int sj = (j == 0) ? S : __builtin_amdgcn_readlane(bndv, idx0 + j);
        int ej = (j == KN - 1) ? E : __builtin_amdgcn_readlane(bndv, idx0 + j + 1);
        int k = sj;
        for (; k + 2 <= ej; k += 2) {
          int s0 = __builtin_amdgcn_readlane(cw, k - S);
          int s1 = __builtin_amdgcn_readlane(cw, k + 1 - S);
          float w0 = __int_as_float(__builtin_amdgcn_readlane(dwu, k - S));
          float w1 = __int_as_float(__builtin_amdgcn_readlane(dwu, k + 1 - S));
          ushort2 u0 = ((const ushort2*)(H + (size_t)s0 * D2))[lane];
          ushort2 u1 = ((const ushort2*)(H + (size_t)s1 * D2))[lane];
          a0[j] += w0 * bf2f(u0.x) + w1 * bf2f(u1.x);
          a1[j] += w0 * bf2f(u0.y) + w1 * bf2f(u1.y);
        }
        if (k < ej) {
          int s0 = __builtin_amdgcn_readlane(cw, k - S);
          float w0 = __int_as_float(__builtin_amdgcn_readlane(dwu, k - S));
          ushort2 u0 = ((const ushort2*)(H + (size_t)s0 * D2))[lane];
          a0[j] += w0 * bf2f(u0.x);
          a1[j] += w0 * bf2f(u0.y);
        }
      }
    } else if (len > 64) {
#pragma unroll
      for (int j = 0; j < KN; j++) {
        int sj = (j == 0) ? S : __builtin_amdgcn_readlane(bndv, idx0 + j);
        int ej = (j == KN - 1) ? E : __builtin_amdgcn_readlane(bndv, idx0 + j + 1);
        for (int k = sj; k < ej; k++) {
          int sv = col[k];
          float w = dis[sv];
          ushort2 u = ((const ushort2*)(H + (size_t)sv * D2))[lane];
          a0[j] += w * bf2f(u.x);
          a1[j] += w * bf2f(u.y);
        }
      }
    }
  }
  __syncthreads();
}

#define AGG_GROUP1(BNDV, NXT0)                                                \
  for (int bsub = 0; bsub < 4; bsub++) {                                      \
    int idx0 = bsub * 16;                                                     \
    int endv = (bsub == 3) ? (NXT0)                                           \
                           : __builtin_amdgcn_readlane(BNDV, idx0 + 16);      \
    agg_bucket1(active, lane, BNDV, idx0, endv, H, col, dis, a0, a1, a2, a3); \
  }

#define AGG_GROUP2(BNDV, NXT0)                                                \
  for (int bsub = 0; bsub < 4; bsub++) {                                      \
    int idx0 = bsub * 16;                                                     \
    int endv = (bsub == 3) ? (NXT0)                                           \
                           : __builtin_amdgcn_readlane(BNDV, idx0 + 16);      \
    agg_bucket2(active, lane, BNDV, idx0, endv, H, col, dis, a0, a1);         \
  }

__global__ __launch_bounds__(256, 4) void k_agg1(const unsigned short* __restrict__ H,
                                                 const int* __restrict__ bptr,
                                                 const int* __restrict__ col,
                                                 const float* __restrict__ dis,
                                                 const float* __restrict__ bias,
                                                 unsigned short* __restrict__ OUT) {
  const int lane = threadIdx.x & 63;
  const int c = blockIdx.x * 4 + (threadIdx.x >> 6);
  const bool active = (c < NCHUNK);

  float a0[KN], a1[KN], a2[KN], a3[KN];
  int bnd0 = 0, bnd1 = 0, bnd2 = 0, bnd3 = 0, segend = 0;
  if (active) {
    const int* bp = bptr + (size_t)c * 256;
    bnd0 = bp[lane]; bnd1 = bp[64 + lane]; bnd2 = bp[128 + lane]; bnd3 = bp[192 + lane];
    segend = bp[256];
#pragma unroll
    for (int j = 0; j < KN; j++) {
      int n = c * KN + j;
      float d = dis[n];
      ushort4 v = ((const ushort4*)(H + (size_t)n * D1))[lane];
      a0[j] = d * bf2f(v.x); a1[j] = d * bf2f(v.y);
      a2[j] = d * bf2f(v.z); a3[j] = d * bf2f(v.w);
    }
  } else {
#pragma unroll
    for (int j = 0; j < KN; j++) a0[j] = a1[j] = a2[j] = a3[j] = 0.f;
  }

  AGG_GROUP1(bnd0, __builtin_amdgcn_readlane(bnd1, 0))
  AGG_GROUP1(bnd1, __builtin_amdgcn_readlane(bnd2, 0))
  AGG_GROUP1(bnd2, __builtin_amdgcn_readlane(bnd3, 0))
  AGG_GROUP1(bnd3, segend)

  if (active) {
    float4 bb = ((const float4*)bias)[lane];
#pragma unroll
    for (int j = 0; j < KN; j++) {
      int n = c * KN + j;
      float d = dis[n];
      ushort4 o;
      o.x = f2bf(fmaf(d, a0[j], bb.x));
      o.y = f2bf(fmaf(d, a1[j], bb.y));
      o.z = f2bf(fmaf(d, a2[j], bb.z));
      o.w = f2bf(fmaf(d, a3[j], bb.w));
      ((ushort4*)(OUT + (size_t)n * D1))[lane] = o;
    }
  }
}

__global__ __launch_bounds__(256, 4) void k_agg2(const unsigned short* __restrict__ H,
                                                 const int* __restrict__ bptr,
                                                 const int* __restrict__ col,
                                                 const float* __restrict__ dis,
                                                 const float* __restrict__ bias,
                                                 float* __restrict__ OUT) {
  const int lane = threadIdx.x & 63;
  const int c = blockIdx.x * 4 + (threadIdx.x >> 6);
  const bool active = (c < NCHUNK);

  float a0[KN], a1[KN];
  int bnd0 = 0, bnd1 = 0, bnd2 = 0, bnd3 = 0, segend = 0;
  if (active) {
    const int* bp = bptr + (size_t)c * 256;
    bnd0 = bp[lane]; bnd1 = bp[64 + lane]; bnd2 = bp[128 + lane]; bnd3 = bp[192 + lane];
    segend = bp[256];
#pragma unroll
    for (int j = 0; j < KN; j++) {
      int n = c * KN + j;
      float d = dis[n];
      ushort2 v = ((const ushort2*)(H + (size_t)n * D2))[lane];
      a0[j] = d * bf2f(v.x); a1[j] = d * bf2f(v.y);
    }
  } else {
#pragma unroll
    for (int j = 0; j < KN; j++) a0[j] = a1[j] = 0.f;
  }

  AGG_GROUP2(bnd0, __builtin_amdgcn_readlane(bnd1, 0))
  AGG_GROUP2(bnd1, __builtin_amdgcn_readlane(bnd2, 0))
  AGG_GROUP2(bnd2, __builtin_amdgcn_readlane(bnd3, 0))
  AGG_GROUP2(bnd3, segend)

  if (active) {
    float2 bb = ((const float2*)bias)[lane];
#pragma unroll
    for (int j = 0; j < KN; j++) {
      int n = c * KN + j;
      float d = dis[n];
      ((float2*)(OUT + (size_t)n * D2))[lane] =
          make_float2(fmaf(d, a0[j], bb.x), fmaf(d, a1[j], bb.y));
    }
  }
}

// ---------- BatchNorm stats ----------
__global__ void k_stats1(const unsigned short* __restrict__ X, float* __restrict__ stats) {
  int t = threadIdx.x;  // column 0..255
  int r0 = blockIdx.x * 64;
  int r1 = (r0 + 64 < NN) ? r0 + 64 : NN;
  float s = 0.f, q = 0.f;
  for (int r = r0; r < r1; r++) {
    float v = bf2f(X[(size_t)r * D1 + t]);
    s += v;
    q += v * v;
  }
  atomicAdd(&stats[t], s);
  atomicAdd(&stats[D1 + t], q);
}

__global__ void k_stats2(const float* __restrict__ X, float* __restrict__ stats) {
  int t = threadIdx.x;  // column 0..127
  int r0 = blockIdx.x * 128;
  int r1 = (r0 + 128 < NN) ? r0 + 128 : NN;
  float s = 0.f, q = 0.f;
  for (int r = r0; r < r1; r++) {
    float v = X[(size_t)r * D2 + t];
    s += v;
    q += v * v;
  }
  atomicAdd(&stats[t], s);
  atomicAdd(&stats[D2 + t], q);
}

__global__ void k_apply2(float* __restrict__ X, const float* __restrict__ stats,
                         const float* __restrict__ gamma, const float* __restrict__ beta) {
  int i = blockIdx.x * blockDim.x + threadIdx.x;
  int c = i & (D2 - 1);
  float mean = stats[c] * (1.0f / NN);
  float var = stats[D2 + c] * (1.0f / NN) - mean * mean;
  float sc = gamma[c] * rsqrtf(var + EPSV);
  X[i] = (X[i] - mean) * sc + beta[c];
}

extern "C" void kernel_launch(void* const* d_in, const int* in_sizes, int n_in,
                              void* d_out, int out_size, void* d_ws, size_t ws_size,
                              hipStream_t stream) {
  const float* x  = (const float*)d_in[0];
  const int* ei   = (const int*)d_in[1];  // [2, NE], int32
  const int* srcv = ei;
  const int* dstv = ei + NE;
  const float* W1  = (const float*)d_in[2];
  const float* b1  = (const float*)d_in[3];
  const float* g1  = (const float*)d_in[4];
  const float* be1 = (const float*)d_in[5];
  const float* W2  = (const float*)d_in[6];
  const float* b2  = (const float*)d_in[7];
  const float* g2  = (const float*)d_in[8];
  const float* be2 = (const float*)d_in[9];
  float* out = (float*)d_out;

  char* ws = (char*)d_ws;
  size_t off = 0;
  auto alloc = [&](size_t bytes) {
    size_t cur = off;
    off = (off + bytes + 255) & ~(size_t)255;
    return cur;
  };
  float* dis     = (float*)(ws + alloc(NN * 4));
  int* gcursor   = (int*)(ws + alloc(NDB * 4));
  int* ebase     = (int*)(ws + alloc((NDB + 1) * 4));
  float* stats   = (float*)(ws + alloc((D1 * 2 + D2 * 2) * 4));
  float* sc1     = (float*)(ws + alloc(D1 * 4));
  float* sh1     = (float*)(ws + alloc(D1 * 4));
  int* bptr      = (int*)(ws + alloc(((size_t)NCHUNK * 256 + 1) * 4));
  int* col       = (int*)(ws + alloc((size_t)NE * 4));
  unsigned short* H1  = (unsigned short*)(ws + alloc((size_t)NN * D1 * 2));
  unsigned short* A1  = (unsigned short*)(ws + alloc((size_t)NN * D1 * 2));
  unsigned short* H2  = (unsigned short*)(ws + alloc((size_t)NN * D2 * 2));
  unsigned short* W1t = (unsigned short*)(ws + alloc((size_t)DIN * D1 * 2));
  unsigned short* W2t = (unsigned short*)(ws + alloc((size_t)D1 * D2 * 2));
  float* stats2 = stats + D1 * 2;
  // part aliases H1 (dead until k_gemm1; 125*16384*4 = 8.2 MB <= 25.6 MB)
  unsigned int* part = (unsigned int*)H1;

  // CSR build: partition -> bucket scan -> per-bucket counting sort
  k_zero<<<3, 256, 0, stream>>>(gcursor, stats);
  k_part<<<256, 256, 0, stream>>>(srcv, dstv, gcursor, part);
  k_bscan<<<1, 128, 0, stream>>>(gcursor, ebase);
  k_build<<<NDB, 256, 0, stream>>>(part, gcursor, ebase, bptr, dis, col);

  // weight transpose + bf16 convert
  k_prep_w<<<(DIN * D1 + D1 * D2) / 256, 256, 0, stream>>>(W1, W2, W1t, W2t);

  const int mb = (NN + 127) / 128;  // 391

  // conv1
  k_gemm1<<<mb, 512, 0, stream>>>(x, W1t, H1, NN);
  k_agg1<<<AGG_GRID, 256, 0, stream>>>(H1, bptr, col, dis, b1, A1);
  k_stats1<<<(NN + 63) / 64, 256, 0, stream>>>(A1, stats);
  k_finalize1<<<1, 256, 0, stream>>>(stats, g1, be1, sc1, sh1);

  // conv2
  k_gemm2<<<mb, 256, 0, stream>>>(A1, sc1, sh1, W2t, H2, NN);
  k_agg2<<<AGG_GRID, 256, 0, stream>>>(H2, bptr, col, dis, b2, out);
  k_stats2<<<(NN + 127) / 128, 128, 0, stream>>>(out, stats2);
  k_apply2<<<NN * D2 / 256, 256, 0, stream>>>(out, stats2, g2, be2);
}

// Round 6
// 516.136 us; speedup vs baseline: 1.2964x; 1.2964x over previous
//
#include <hip/hip_runtime.h>
#include <hip/hip_bf16.h>

// GCN encoder: conv1(512->256) -> BN -> ReLU -> conv2(256->128) -> BN
// R12: R11 with the gemm1 B-staging bug fixed. R11 regression cause: moving
// gemm1 512->256 threads kept chunk=wave*4+j (16 chunks = 128 rows) so only
// half of Bs[256][64] was staged -> absmax 4.37. Now chunk=wave*8+j (32
// chunks = 256 rows). gemm2 was already correct (2 waves x 8 chunks = 128).
// R11 intent unchanged: BM=64 GEMMs (782 blocks) fix 391-block wave
// quantization on 256 CUs; agg/CSR are verified R7 code (512.9us baseline).
// Kept from R7: 64-edge blocked agg (coalesced col+dis, readlane broadcast,
// 8-deep SGPR-base gathers), two-pass LDS counting-sort CSR build, BN1+ReLU
// fused in gemm2 staging, part[] aliasing H1.

#define NN 50000
#define NE 1600000
#define DIN 512
#define D1 256
#define D2 128
#define EPSV 1e-5f
#define NBUCK 16    // src buckets (agg L2 lockstep); 4 bits in packed word
#define BSZ 3125    // nodes per src bucket (16*3125 = 50000)
#define NDB 128     // dst buckets (CSR build)
#define NPB 391     // nodes per dst bucket (128*391 = 50048 >= NN)
#define CAP 16384   // part capacity per dst bucket (mean 12500, >30 sigma)

typedef __attribute__((ext_vector_type(8))) short bf16x8_t;
typedef __attribute__((ext_vector_type(4))) float f32x4_t;

__device__ __forceinline__ float bf2f(unsigned short u) {
  return __uint_as_float(((unsigned int)u) << 16);
}
__device__ __forceinline__ unsigned short f2bf(float f) {
  unsigned int u = __float_as_uint(f);
  u += 0x7fffu + ((u >> 16) & 1u);   // RNE
  return (unsigned short)(u >> 16);
}
__device__ __forceinline__ unsigned int pk2(float a, float b) {
  __hip_bfloat162 h = __float22bfloat162_rn(make_float2(a, b));
  union { __hip_bfloat162 h; unsigned int u; } c;
  c.h = h;
  return c.u;
}

// ---------- CSR build: two-pass LDS counting sort ----------
__global__ void k_zero(int* __restrict__ gcursor, float* __restrict__ stats) {
  int i = blockIdx.x * 256 + threadIdx.x;
  if (i < NDB) gcursor[i] = 0;
  if (i < (D1 * 2 + D2 * 2)) stats[i] = 0.0f;
}

// Pass A: partition edges into 128 dst-range buckets (fixed CAP stride).
// packed word: src (16b) | dst_local (9b, <<16) | src_bucket (4b, <<25)
__global__ __launch_bounds__(256) void k_part(const int* __restrict__ src,
                                              const int* __restrict__ dst,
                                              int* __restrict__ gcursor,
                                              unsigned int* __restrict__ part) {
  __shared__ int hist[NDB];
  __shared__ int curs[NDB];
  const int t = threadIdx.x;
  const int EB = NE / 256;  // 6250 edges per block
  const int e0 = blockIdx.x * EB;
  if (t < NDB) hist[t] = 0;
  __syncthreads();
  for (int i = t; i < EB; i += 256) {
    int d = dst[e0 + i];
    atomicAdd(&hist[d / NPB], 1);
  }
  __syncthreads();
  if (t < NDB) {
    int c = hist[t];
    curs[t] = (c > 0) ? atomicAdd(&gcursor[t], c) : 0;
  }
  __syncthreads();
  for (int i = t; i < EB; i += 256) {
    int s = src[e0 + i];
    int d = dst[e0 + i];
    int b = d / NPB;
    int dl = d - b * NPB;
    int sb = (unsigned)s / BSZ;
    unsigned int w = (unsigned)s | ((unsigned)dl << 16) | ((unsigned)sb << 25);
    int pos = atomicAdd(&curs[b], 1);
    if (pos < CAP) part[(size_t)b * CAP + pos] = w;
  }
}

// exclusive prefix over 128 bucket totals -> ebase
__global__ void k_bscan(const int* __restrict__ gcursor, int* __restrict__ ebase) {
  __shared__ int s[NDB];
  int t = threadIdx.x;  // blockDim = 128
  int v = gcursor[t];
  s[t] = v;
  __syncthreads();
  for (int off = 1; off < NDB; off <<= 1) {
    int a = (t >= off) ? s[t - off] : 0;
    __syncthreads();
    s[t] += a;
    __syncthreads();
  }
  ebase[t] = s[t] - v;
  if (t == NDB - 1) ebase[NDB] = s[t];
}

// Pass B: per dst-bucket LDS counting sort by (node_local, src_bucket).
// Emits row_ptr, dis, and col (bucket-sorted per node, dense segment).
__global__ __launch_bounds__(256) void k_build(const unsigned int* __restrict__ part,
                                               const int* __restrict__ gcursor,
                                               const int* __restrict__ ebase,
                                               int* __restrict__ row_ptr,
                                               float* __restrict__ dis,
                                               int* __restrict__ col) {
  const int NC = NPB * NBUCK;  // 6256 counters
  __shared__ int cnt[NC];
  __shared__ int tsum[256];
  const int b = blockIdx.x, t = threadIdx.x;
  int m = gcursor[b];
  if (m > CAP) m = CAP;
  const int base = ebase[b];
  const unsigned int* my = part + (size_t)b * CAP;
  for (int i = t; i < NC; i += 256) cnt[i] = 0;
  __syncthreads();
  for (int i = t; i < m; i += 256) {
    unsigned int w = my[i];
    atomicAdd(&cnt[((w >> 16) & 0x1ff) * NBUCK + (w >> 25)], 1);
  }
  __syncthreads();
  // exclusive scan of cnt[0..NC)
  const int CHK = (NC + 255) / 256;  // 25
  int i0 = t * CHK;
  int sum = 0;
  for (int i = 0; i < CHK; i++) {
    int idx = i0 + i;
    if (idx < NC) sum += cnt[idx];
  }
  tsum[t] = sum;
  __syncthreads();
  for (int off = 1; off < 256; off <<= 1) {
    int a = (t >= off) ? tsum[t - off] : 0;
    __syncthreads();
    tsum[t] += a;
    __syncthreads();
  }
  int run = tsum[t] - sum;
  for (int i = 0; i < CHK; i++) {
    int idx = i0 + i;
    if (idx < NC) {
      int c = cnt[idx];
      cnt[idx] = run;
      run += c;
    }
  }
  __syncthreads();
  // row_ptr / dis from scan values
  const int n0 = b * NPB;
  for (int dl = t; dl < NPB; dl += 256) {
    int n = n0 + dl;
    if (n < NN) {
      int st = cnt[dl * NBUCK];
      int en = (dl * NBUCK + NBUCK < NC) ? cnt[dl * NBUCK + NBUCK] : m;
      row_ptr[n] = base + st;
      dis[n] = rsqrtf((float)(en - st + 1));  // +1 self loop
    }
  }
  if (b == NDB - 1 && t == 0) row_ptr[NN] = base + m;
  __syncthreads();
  // scatter (cnt now serves as cursors); col segment [base, base+m) is dense
  for (int i = t; i < m; i += 256) {
    unsigned int w = my[i];
    int pos = atomicAdd(&cnt[((w >> 16) & 0x1ff) * NBUCK + (w >> 25)], 1);
    col[base + pos] = w & 0xffff;
  }
}

// ---------- weight prep: W [KxN] fp32 -> Wt [NxK] bf16 ----------
__global__ void k_prep_w(const float* __restrict__ W1, const float* __restrict__ W2,
                         unsigned short* __restrict__ W1t, unsigned short* __restrict__ W2t) {
  int i = blockIdx.x * 256 + threadIdx.x;
  if (i < DIN * D1) {  // W1t[n*DIN + k] = W1[k*D1 + n]
    int n = i / DIN, k = i - n * DIN;
    W1t[i] = f2bf(W1[(size_t)k * D1 + n]);
  } else {
    int j = i - DIN * D1;  // W2t[n*D1 + k] = W2[k*D2 + n]
    int n = j / D1, k = j - n * D1;
    W2t[j] = f2bf(W2[(size_t)k * D2 + n]);
  }
}

// ---------- GEMM1: H1[M x 256] = x[M x 512] @ W1t[256 x 512]^T ----------
// R12: BM=64 (782 blocks); 256 threads = 4 waves in 1x4 N-grid, 64Mx64N each.
// B staged as 32 chunks (8/wave) x 8 rows = all 256 Bs rows (R11 bug fixed).
__global__ __launch_bounds__(256) void k_gemm1(const float* __restrict__ A,
                                               const unsigned short* __restrict__ Bt,
                                               unsigned short* __restrict__ C, int M) {
  __shared__ unsigned short As[64 * 64];
  __shared__ unsigned short Bs[256 * 64];
  const int t = threadIdx.x;
  const int wave = t >> 6, lane = t & 63;
  const int m0 = blockIdx.x * 64;
  const int wn = wave * 64;
  const int l8 = lane >> 3;
  const int lbs = (lane & 7) ^ l8;
  const int row_c = lane & 15, quad = lane >> 4;

  f32x4_t acc[4][4];
#pragma unroll
  for (int i = 0; i < 4; i++)
#pragma unroll
    for (int j = 0; j < 4; j++) acc[i][j] = (f32x4_t){0.f, 0.f, 0.f, 0.f};

  for (int k0 = 0; k0 < DIN; k0 += 64) {
#pragma unroll
    for (int j = 0; j < 8; j++) {
      int chunk = wave * 8 + j;  // 32 chunks x 8 rows = 256 B-rows
      int row = chunk * 8 + l8;
      const unsigned short* g = Bt + (size_t)row * DIN + k0 + lbs * 8;
      __builtin_amdgcn_global_load_lds(
          (const __attribute__((address_space(1))) unsigned int*)g,
          (__attribute__((address_space(3))) unsigned int*)(Bs + chunk * 512), 16, 0, 0);
    }
#pragma unroll
    for (int i = 0; i < 2; i++) {
      int bid = i * 256 + t;  // 64 rows x 8 slots = 512 slots
      int row = bid >> 3, pb = bid & 7;
      int lb = pb ^ (row & 7);
      int gm = m0 + row;
      if (gm >= M) gm = M - 1;
      const float4* s = (const float4*)(A + (size_t)gm * DIN + k0 + lb * 8);
      float4 v0 = s[0], v1 = s[1];
      uint4 o;
      o.x = pk2(v0.x, v0.y);
      o.y = pk2(v0.z, v0.w);
      o.z = pk2(v1.x, v1.y);
      o.w = pk2(v1.z, v1.w);
      *(uint4*)(As + row * 64 + pb * 8) = o;
    }
    __syncthreads();
#pragma unroll
    for (int ki = 0; ki < 2; ki++) {
      bf16x8_t af[4], bfr[4];
      int kb = ki * 4 + quad;
#pragma unroll
      for (int i = 0; i < 4; i++) {
        int ar = i * 16 + row_c;
        af[i] = *(const bf16x8_t*)(As + ar * 64 + ((kb ^ (ar & 7)) * 8));
        int br = wn + i * 16 + row_c;
        bfr[i] = *(const bf16x8_t*)(Bs + br * 64 + ((kb ^ (br & 7)) * 8));
      }
#pragma unroll
      for (int i = 0; i < 4; i++)
#pragma unroll
        for (int j = 0; j < 4; j++)
          acc[i][j] = __builtin_amdgcn_mfma_f32_16x16x32_bf16(af[i], bfr[j], acc[i][j], 0, 0, 0);
    }
    __syncthreads();
  }
#pragma unroll
  for (int i = 0; i < 4; i++) {
#pragma unroll
    for (int j = 0; j < 4; j++) {
      int colv = wn + j * 16 + row_c;
#pragma unroll
      for (int r = 0; r < 4; r++) {
        int gm = m0 + i * 16 + quad * 4 + r;
        if (gm < M) C[(size_t)gm * D1 + colv] = f2bf(acc[i][j][r]);
      }
    }
  }
}

// per-column BN1 scale/shift from stats
__global__ void k_finalize1(const float* __restrict__ stats, const float* __restrict__ gamma,
                            const float* __restrict__ beta, float* __restrict__ sc1,
                            float* __restrict__ sh1) {
  int c = threadIdx.x;  // 256
  float mean = stats[c] * (1.0f / NN);
  float var = stats[D1 + c] * (1.0f / NN) - mean * mean;
  float sc = gamma[c] * rsqrtf(var + EPSV);
  sc1[c] = sc;
  sh1[c] = beta[c] - mean * sc;
}

// ---------- GEMM2: H2[M x 128] = relu(BN(A1))[M x 256] @ W2t[128 x 256]^T ----------
// BM=64 (782 blocks), 128 threads = 2 waves in 1x2 N-grid, 64x64 each.
__global__ __launch_bounds__(128) void k_gemm2(const unsigned short* __restrict__ A,
                                               const float* __restrict__ sc1,
                                               const float* __restrict__ sh1,
                                               const unsigned short* __restrict__ Bt,
                                               unsigned short* __restrict__ C, int M) {
  __shared__ unsigned short As[64 * 64];
  __shared__ unsigned short Bs[128 * 64];
  const int t = threadIdx.x;
  const int wave = t >> 6, lane = t & 63;
  const int m0 = blockIdx.x * 64;
  const int wn = wave * 64;
  const int l8 = lane >> 3;
  const int lbs = (lane & 7) ^ l8;
  const int row_c = lane & 15, quad = lane >> 4;

  f32x4_t acc[4][4];
#pragma unroll
  for (int i = 0; i < 4; i++)
#pragma unroll
    for (int j = 0; j < 4; j++) acc[i][j] = (f32x4_t){0.f, 0.f, 0.f, 0.f};

  for (int k0 = 0; k0 < D1; k0 += 64) {
#pragma unroll
    for (int j = 0; j < 8; j++) {
      int chunk = wave * 8 + j;  // 16 chunks x 8 rows = 128 B-rows
      int row = chunk * 8 + l8;
      const unsigned short* g = Bt + (size_t)row * D1 + k0 + lbs * 8;
      __builtin_amdgcn_global_load_lds(
          (const __attribute__((address_space(1))) unsigned int*)g,
          (__attribute__((address_space(3))) unsigned int*)(Bs + chunk * 512), 16, 0, 0);
    }
#pragma unroll
    for (int i = 0; i < 4; i++) {
      int bid = i * 128 + t;  // 64 rows x 8 slots = 512 slots
      int row = bid >> 3, pb = bid & 7;
      int lb = pb ^ (row & 7);
      int gm = m0 + row;
      if (gm >= M) gm = M - 1;
      int colb = k0 + lb * 8;
      uint4 raw = *(const uint4*)(A + (size_t)gm * D1 + colb);
      float4 scA = *(const float4*)(sc1 + colb);
      float4 scB = *(const float4*)(sc1 + colb + 4);
      float4 shA = *(const float4*)(sh1 + colb);
      float4 shB = *(const float4*)(sh1 + colb + 4);
      float f0 = fmaxf(fmaf(bf2f((unsigned short)(raw.x & 0xffff)), scA.x, shA.x), 0.f);
      float f1 = fmaxf(fmaf(bf2f((unsigned short)(raw.x >> 16)),    scA.y, shA.y), 0.f);
      float f2 = fmaxf(fmaf(bf2f((unsigned short)(raw.y & 0xffff)), scA.z, shA.z), 0.f);
      float f3 = fmaxf(fmaf(bf2f((unsigned short)(raw.y >> 16)),    scA.w, shA.w), 0.f);
      float f4 = fmaxf(fmaf(bf2f((unsigned short)(raw.z & 0xffff)), scB.x, shB.x), 0.f);
      float f5 = fmaxf(fmaf(bf2f((unsigned short)(raw.z >> 16)),    scB.y, shB.y), 0.f);
      float f6 = fmaxf(fmaf(bf2f((unsigned short)(raw.w & 0xffff)), scB.z, shB.z), 0.f);
      float f7 = fmaxf(fmaf(bf2f((unsigned short)(raw.w >> 16)),    scB.w, shB.w), 0.f);
      uint4 o;
      o.x = pk2(f0, f1);
      o.y = pk2(f2, f3);
      o.z = pk2(f4, f5);
      o.w = pk2(f6, f7);
      *(uint4*)(As + row * 64 + pb * 8) = o;
    }
    __syncthreads();
#pragma unroll
    for (int ki = 0; ki < 2; ki++) {
      bf16x8_t af[4], bfr[4];
      int kb = ki * 4 + quad;
#pragma unroll
      for (int i = 0; i < 4; i++) {
        int ar = i * 16 + row_c;
        af[i] = *(const bf16x8_t*)(As + ar * 64 + ((kb ^ (ar & 7)) * 8));
        int br = wn + i * 16 + row_c;
        bfr[i] = *(const bf16x8_t*)(Bs + br * 64 + ((kb ^ (br & 7)) * 8));
      }
#pragma unroll
      for (int i = 0; i < 4; i++)
#pragma unroll
        for (int j = 0; j < 4; j++)
          acc[i][j] = __builtin_amdgcn_mfma_f32_16x16x32_bf16(af[i], bfr[j], acc[i][j], 0, 0, 0);
    }
    __syncthreads();
  }
#pragma unroll
  for (int i = 0; i < 4; i++) {
#pragma unroll
    for (int j = 0; j < 4; j++) {
      int colv = wn + j * 16 + row_c;  // < 128 = D2
#pragma unroll
      for (int r = 0; r < 4; r++) {
        int gm = m0 + i * 16 + quad * 4 + r;
        if (gm < M) C[(size_t)gm * D2 + colv] = f2bf(acc[i][j][r]);
      }
    }
  }
}

// ---------- CSR aggregation: one wave per node, 64-edge blocked (R7) ----------
// Per 64-edge block: one coalesced col load + one dis gather; v_readlane
// broadcasts (src, weight) to SGPRs so row gathers are saddr loads issued
// 8-deep ahead of the FMAs that consume them.
__global__ __launch_bounds__(256) void k_agg1(const unsigned short* __restrict__ H,
                                              const int* __restrict__ row_ptr,
                                              const int* __restrict__ col,
                                              const float* __restrict__ dis,
                                              const float* __restrict__ bias,
                                              unsigned short* __restrict__ OUT) {
  int n = blockIdx.x * 4 + (threadIdx.x >> 6);
  int lane = threadIdx.x & 63;
  if (n >= NN) return;
  float dn = dis[n];
  ushort4 v = ((const ushort4*)(H + (size_t)n * D1))[lane];
  float wsf = dn * dn;
  float a0 = wsf * bf2f(v.x), a1 = wsf * bf2f(v.y);
  float a2 = wsf * bf2f(v.z), a3 = wsf * bf2f(v.w);
  int e = row_ptr[n], e1 = row_ptr[n + 1];
  while (e < e1) {
    int cnt = e1 - e;
    if (cnt > 64) cnt = 64;
    int li = (lane < cnt) ? lane : (cnt - 1);
    int cv = col[e + li];                 // 64 edges' src ids, one load
    float dwv = dis[cv] * dn;             // 64 edges' weights, one gather
    int dwu = __float_as_int(dwv);
    int b = 0;
    for (; b + 8 <= cnt; b += 8) {
      int s[8];
      float w[8];
      ushort4 u[8];
#pragma unroll
      for (int k = 0; k < 8; k++) {
        s[k] = __builtin_amdgcn_readlane(cv, b + k);
        w[k] = __int_as_float(__builtin_amdgcn_readlane(dwu, b + k));
      }
#pragma unroll
      for (int k = 0; k < 8; k++)
        u[k] = ((const ushort4*)(H + (size_t)s[k] * D1))[lane];
#pragma unroll
      for (int k = 0; k < 8; k++) {
        a0 += w[k] * bf2f(u[k].x);
        a1 += w[k] * bf2f(u[k].y);
        a2 += w[k] * bf2f(u[k].z);
        a3 += w[k] * bf2f(u[k].w);
      }
    }
    for (; b < cnt; b++) {
      int sK = __builtin_amdgcn_readlane(cv, b);
      float wK = __int_as_float(__builtin_amdgcn_readlane(dwu, b));
      ushort4 uK = ((const ushort4*)(H + (size_t)sK * D1))[lane];
      a0 += wK * bf2f(uK.x);
      a1 += wK * bf2f(uK.y);
      a2 += wK * bf2f(uK.z);
      a3 += wK * bf2f(uK.w);
    }
    e += cnt;
  }
  int c = lane * 4;
  a0 += bias[c]; a1 += bias[c + 1]; a2 += bias[c + 2]; a3 += bias[c + 3];
  ushort4 o;
  o.x = f2bf(a0); o.y = f2bf(a1); o.z = f2bf(a2); o.w = f2bf(a3);
  ((ushort4*)(OUT + (size_t)n * D1))[lane] = o;
}

__global__ __launch_bounds__(256) void k_agg2(const unsigned short* __restrict__ H,
                                              const int* __restrict__ row_ptr,
                                              const int* __restrict__ col,
                                              const float* __restrict__ dis,
                                              const float* __restrict__ bias,
                                              float* __restrict__ OUT) {
  int n = blockIdx.x * 4 + (threadIdx.x >> 6);
  int lane = threadIdx.x & 63;
  if (n >= NN) return;
  float dn = dis[n];
  ushort2 v = ((const ushort2*)(H + (size_t)n * D2))[lane];
  float wsf = dn * dn;
  float a0 = wsf * bf2f(v.x), a1 = wsf * bf2f(v.y);
  int e = row_ptr[n], e1 = row_ptr[n + 1];
  while (e < e1) {
    int cnt = e1 - e;
    if (cnt > 64) cnt = 64;
    int li = (lane < cnt) ? lane : (cnt - 1);
    int cv = col[e + li];
    float dwv = dis[cv] * dn;
    int dwu = __float_as_int(dwv);
    int b = 0;
    for (; b + 8 <= cnt; b += 8) {
      int s[8];
      float w[8];
      ushort2 u[8];
#pragma unroll
      for (int k = 0; k < 8; k++) {
        s[k] = __builtin_amdgcn_readlane(cv, b + k);
        w[k] = __int_as_float(__builtin_amdgcn_readlane(dwu, b + k));
      }
#pragma unroll
      for (int k = 0; k < 8; k++)
        u[k] = ((const ushort2*)(H + (size_t)s[k] * D2))[lane];
#pragma unroll
      for (int k = 0; k < 8; k++) {
        a0 += w[k] * bf2f(u[k].x);
        a1 += w[k] * bf2f(u[k].y);
      }
    }
    for (; b < cnt; b++) {
      int sK = __builtin_amdgcn_readlane(cv, b);
      float wK = __int_as_float(__builtin_amdgcn_readlane(dwu, b));
      ushort2 uK = ((const ushort2*)(H + (size_t)sK * D2))[lane];
      a0 += wK * bf2f(uK.x);
      a1 += wK * bf2f(uK.y);
    }
    e += cnt;
  }
  int c = lane * 2;
  a0 += bias[c]; a1 += bias[c + 1];
  ((float2*)(OUT + (size_t)n * D2))[lane] = make_float2(a0, a1);
}

// ---------- BatchNorm stats ----------
__global__ void k_stats1(const unsigned short* __restrict__ X, float* __restrict__ stats) {
  int t = threadIdx.x;  // column 0..255
  int r0 = blockIdx.x * 64;
  int r1 = (r0 + 64 < NN) ? r0 + 64 : NN;
  float s = 0.f, q = 0.f;
  for (int r = r0; r < r1; r++) {
    float v = bf2f(X[(size_t)r * D1 + t]);
    s += v;
    q += v * v;
  }
  atomicAdd(&stats[t], s);
  atomicAdd(&stats[D1 + t], q);
}

__global__ void k_stats2(const float* __restrict__ X, float* __restrict__ stats) {
  int t = threadIdx.x;  // column 0..127
  int r0 = blockIdx.x * 128;
  int r1 = (r0 + 128 < NN) ? r0 + 128 : NN;
  float s = 0.f, q = 0.f;
  for (int r = r0; r < r1; r++) {
    float v = X[(size_t)r * D2 + t];
    s += v;
    q += v * v;
  }
  atomicAdd(&stats[t], s);
  atomicAdd(&stats[D2 + t], q);
}

__global__ void k_apply2(float* __restrict__ X, const float* __restrict__ stats,
                         const float* __restrict__ gamma, const float* __restrict__ beta) {
  int i = blockIdx.x * blockDim.x + threadIdx.x;
  int c = i & (D2 - 1);
  float mean = stats[c] * (1.0f / NN);
  float var = stats[D2 + c] * (1.0f / NN) - mean * mean;
  float sc = gamma[c] * rsqrtf(var + EPSV);
  X[i] = (X[i] - mean) * sc + beta[c];
}

extern "C" void kernel_launch(void* const* d_in, const int* in_sizes, int n_in,
                              void* d_out, int out_size, void* d_ws, size_t ws_size,
                              hipStream_t stream) {
  const float* x  = (const float*)d_in[0];
  const int* ei   = (const int*)d_in[1];  // [2, NE], int32
  const int* srcv = ei;
  const int* dstv = ei + NE;
  const float* W1  = (const float*)d_in[2];
  const float* b1  = (const float*)d_in[3];
  const float* g1  = (const float*)d_in[4];
  const float* be1 = (const float*)d_in[5];
  const float* W2  = (const float*)d_in[6];
  const float* b2  = (const float*)d_in[7];
  const float* g2  = (const float*)d_in[8];
  const float* be2 = (const float*)d_in[9];
  float* out = (float*)d_out;

  char* ws = (char*)d_ws;
  size_t off = 0;
  auto alloc = [&](size_t bytes) {
    size_t cur = off;
    off = (off + bytes + 255) & ~(size_t)255;
    return cur;
  };
  int* row_ptr   = (int*)(ws + alloc((NN + 1) * 4));
  float* dis     = (float*)(ws + alloc(NN * 4));
  int* gcursor   = (int*)(ws + alloc(NDB * 4));
  int* ebase     = (int*)(ws + alloc((NDB + 1) * 4));
  float* stats   = (float*)(ws + alloc((D1 * 2 + D2 * 2) * 4));
  float* sc1     = (float*)(ws + alloc(D1 * 4));
  float* sh1     = (float*)(ws + alloc(D1 * 4));
  int* col       = (int*)(ws + alloc((size_t)NE * 4));
  unsigned short* H1  = (unsigned short*)(ws + alloc((size_t)NN * D1 * 2));
  unsigned short* A1  = (unsigned short*)(ws + alloc((size_t)NN * D1 * 2));
  unsigned short* H2  = (unsigned short*)(ws + alloc((size_t)NN * D2 * 2));
  unsigned short* W1t = (unsigned short*)(ws + alloc((size_t)DIN * D1 * 2));
  unsigned short* W2t = (unsigned short*)(ws + alloc((size_t)D1 * D2 * 2));
  float* stats2 = stats + D1 * 2;
  // part aliases H1 (dead until k_gemm1; 8.4 MB <= 25.6 MB)
  unsigned int* part = (unsigned int*)H1;

  // CSR build: partition -> bucket scan -> per-bucket counting sort
  k_zero<<<3, 256, 0, stream>>>(gcursor, stats);
  k_part<<<256, 256, 0, stream>>>(srcv, dstv, gcursor, part);
  k_bscan<<<1, NDB, 0, stream>>>(gcursor, ebase);
  k_build<<<NDB, 256, 0, stream>>>(part, gcursor, ebase, row_ptr, dis, col);

  // weight transpose + bf16 convert
  k_prep_w<<<(DIN * D1 + D1 * D2) / 256, 256, 0, stream>>>(W1, W2, W1t, W2t);

  const int mb = (NN + 63) / 64;  // 782

  // conv1
  k_gemm1<<<mb, 256, 0, stream>>>(x, W1t, H1, NN);
  k_agg1<<<(NN + 3) / 4, 256, 0, stream>>>(H1, row_ptr, col, dis, b1, A1);
  k_stats1<<<(NN + 63) / 64, 256, 0, stream>>>(A1, stats);
  k_finalize1<<<1, 256, 0, stream>>>(stats, g1, be1, sc1, sh1);

  // conv2
  k_gemm2<<<mb, 128, 0, stream>>>(A1, sc1, sh1, W2t, H2, NN);
  k_agg2<<<(NN + 3) / 4, 256, 0, stream>>>(H2, row_ptr, col, dis, b2, out);
  k_stats2<<<(NN + 127) / 128, 128, 0, stream>>>(out, stats2);
  k_apply2<<<NN * D2 / 256, 256, 0, stream>>>(out, stats2, g2, be2);
}

// Round 7
// 512.689 us; speedup vs baseline: 1.3052x; 1.0067x over previous
//
#include <hip/hip_runtime.h>
#include <hip/hip_bf16.h>

// GCN encoder: conv1(512->256) -> BN -> ReLU -> conv2(256->128) -> BN
// R13: agg1 column-split experiment. R12 baseline (516.1us) with ONE change:
// k_agg1 runs as two 128-column passes (k_agg1h half=0/1). Rationale: agg1 is
// HBM-miss throughput-bound (819MB L2-level gathers, 358MB fetch, 56% hit);
// per-pass working set 25.6->12.8MB cuts per-XCD L2 oversubscription 6.4->3.2x
// -> higher hit rate at same L2-level bytes. Cost: col/dis read twice (+7MB),
// per-edge VALU doubles (38%->~45% busy, still under the memory binder),
// 256B gathers (4 lines) slightly less DRAM-efficient. Single-variable round.
// Kept from R12: BM=64 GEMMs (gemm1 staging bug fixed in R12), R7 streaming
// agg2, two-pass LDS counting-sort CSR build, BN1+ReLU fused in gemm2
// staging, part[] aliasing H1.

#define NN 50000
#define NE 1600000
#define DIN 512
#define D1 256
#define D2 128
#define EPSV 1e-5f
#define NBUCK 16    // src buckets (agg L2 lockstep); 4 bits in packed word
#define BSZ 3125    // nodes per src bucket (16*3125 = 50000)
#define NDB 128     // dst buckets (CSR build)
#define NPB 391     // nodes per dst bucket (128*391 = 50048 >= NN)
#define CAP 16384   // part capacity per dst bucket (mean 12500, >30 sigma)

typedef __attribute__((ext_vector_type(8))) short bf16x8_t;
typedef __attribute__((ext_vector_type(4))) float f32x4_t;

__device__ __forceinline__ float bf2f(unsigned short u) {
  return __uint_as_float(((unsigned int)u) << 16);
}
__device__ __forceinline__ unsigned short f2bf(float f) {
  unsigned int u = __float_as_uint(f);
  u += 0x7fffu + ((u >> 16) & 1u);   // RNE
  return (unsigned short)(u >> 16);
}
__device__ __forceinline__ unsigned int pk2(float a, float b) {
  __hip_bfloat162 h = __float22bfloat162_rn(make_float2(a, b));
  union { __hip_bfloat162 h; unsigned int u; } c;
  c.h = h;
  return c.u;
}

// ---------- CSR build: two-pass LDS counting sort ----------
__global__ void k_zero(int* __restrict__ gcursor, float* __restrict__ stats) {
  int i = blockIdx.x * 256 + threadIdx.x;
  if (i < NDB) gcursor[i] = 0;
  if (i < (D1 * 2 + D2 * 2)) stats[i] = 0.0f;
}

// Pass A: partition edges into 128 dst-range buckets (fixed CAP stride).
// packed word: src (16b) | dst_local (9b, <<16) | src_bucket (4b, <<25)
__global__ __launch_bounds__(256) void k_part(const int* __restrict__ src,
                                              const int* __restrict__ dst,
                                              int* __restrict__ gcursor,
                                              unsigned int* __restrict__ part) {
  __shared__ int hist[NDB];
  __shared__ int curs[NDB];
  const int t = threadIdx.x;
  const int EB = NE / 256;  // 6250 edges per block
  const int e0 = blockIdx.x * EB;
  if (t < NDB) hist[t] = 0;
  __syncthreads();
  for (int i = t; i < EB; i += 256) {
    int d = dst[e0 + i];
    atomicAdd(&hist[d / NPB], 1);
  }
  __syncthreads();
  if (t < NDB) {
    int c = hist[t];
    curs[t] = (c > 0) ? atomicAdd(&gcursor[t], c) : 0;
  }
  __syncthreads();
  for (int i = t; i < EB; i += 256) {
    int s = src[e0 + i];
    int d = dst[e0 + i];
    int b = d / NPB;
    int dl = d - b * NPB;
    int sb = (unsigned)s / BSZ;
    unsigned int w = (unsigned)s | ((unsigned)dl << 16) | ((unsigned)sb << 25);
    int pos = atomicAdd(&curs[b], 1);
    if (pos < CAP) part[(size_t)b * CAP + pos] = w;
  }
}

// exclusive prefix over 128 bucket totals -> ebase
__global__ void k_bscan(const int* __restrict__ gcursor, int* __restrict__ ebase) {
  __shared__ int s[NDB];
  int t = threadIdx.x;  // blockDim = 128
  int v = gcursor[t];
  s[t] = v;
  __syncthreads();
  for (int off = 1; off < NDB; off <<= 1) {
    int a = (t >= off) ? s[t - off] : 0;
    __syncthreads();
    s[t] += a;
    __syncthreads();
  }
  ebase[t] = s[t] - v;
  if (t == NDB - 1) ebase[NDB] = s[t];
}

// Pass B: per dst-bucket LDS counting sort by (node_local, src_bucket).
// Emits row_ptr, dis, and col (bucket-sorted per node, dense segment).
__global__ __launch_bounds__(256) void k_build(const unsigned int* __restrict__ part,
                                               const int* __restrict__ gcursor,
                                               const int* __restrict__ ebase,
                                               int* __restrict__ row_ptr,
                                               float* __restrict__ dis,
                                               int* __restrict__ col) {
  const int NC = NPB * NBUCK;  // 6256 counters
  __shared__ int cnt[NC];
  __shared__ int tsum[256];
  const int b = blockIdx.x, t = threadIdx.x;
  int m = gcursor[b];
  if (m > CAP) m = CAP;
  const int base = ebase[b];
  const unsigned int* my = part + (size_t)b * CAP;
  for (int i = t; i < NC; i += 256) cnt[i] = 0;
  __syncthreads();
  for (int i = t; i < m; i += 256) {
    unsigned int w = my[i];
    atomicAdd(&cnt[((w >> 16) & 0x1ff) * NBUCK + (w >> 25)], 1);
  }
  __syncthreads();
  // exclusive scan of cnt[0..NC)
  const int CHK = (NC + 255) / 256;  // 25
  int i0 = t * CHK;
  int sum = 0;
  for (int i = 0; i < CHK; i++) {
    int idx = i0 + i;
    if (idx < NC) sum += cnt[idx];
  }
  tsum[t] = sum;
  __syncthreads();
  for (int off = 1; off < 256; off <<= 1) {
    int a = (t >= off) ? tsum[t - off] : 0;
    __syncthreads();
    tsum[t] += a;
    __syncthreads();
  }
  int run = tsum[t] - sum;
  for (int i = 0; i < CHK; i++) {
    int idx = i0 + i;
    if (idx < NC) {
      int c = cnt[idx];
      cnt[idx] = run;
      run += c;
    }
  }
  __syncthreads();
  // row_ptr / dis from scan values
  const int n0 = b * NPB;
  for (int dl = t; dl < NPB; dl += 256) {
    int n = n0 + dl;
    if (n < NN) {
      int st = cnt[dl * NBUCK];
      int en = (dl * NBUCK + NBUCK < NC) ? cnt[dl * NBUCK + NBUCK] : m;
      row_ptr[n] = base + st;
      dis[n] = rsqrtf((float)(en - st + 1));  // +1 self loop
    }
  }
  if (b == NDB - 1 && t == 0) row_ptr[NN] = base + m;
  __syncthreads();
  // scatter (cnt now serves as cursors); col segment [base, base+m) is dense
  for (int i = t; i < m; i += 256) {
    unsigned int w = my[i];
    int pos = atomicAdd(&cnt[((w >> 16) & 0x1ff) * NBUCK + (w >> 25)], 1);
    col[base + pos] = w & 0xffff;
  }
}

// ---------- weight prep: W [KxN] fp32 -> Wt [NxK] bf16 ----------
__global__ void k_prep_w(const float* __restrict__ W1, const float* __restrict__ W2,
                         unsigned short* __restrict__ W1t, unsigned short* __restrict__ W2t) {
  int i = blockIdx.x * 256 + threadIdx.x;
  if (i < DIN * D1) {  // W1t[n*DIN + k] = W1[k*D1 + n]
    int n = i / DIN, k = i - n * DIN;
    W1t[i] = f2bf(W1[(size_t)k * D1 + n]);
  } else {
    int j = i - DIN * D1;  // W2t[n*D1 + k] = W2[k*D2 + n]
    int n = j / D1, k = j - n * D1;
    W2t[j] = f2bf(W2[(size_t)k * D2 + n]);
  }
}

// ---------- GEMM1: H1[M x 256] = x[M x 512] @ W1t[256 x 512]^T ----------
// BM=64 (782 blocks); 256 threads = 4 waves in 1x4 N-grid, 64Mx64N each.
// B staged as 32 chunks (8/wave) x 8 rows = all 256 Bs rows.
__global__ __launch_bounds__(256) void k_gemm1(const float* __restrict__ A,
                                               const unsigned short* __restrict__ Bt,
                                               unsigned short* __restrict__ C, int M) {
  __shared__ unsigned short As[64 * 64];
  __shared__ unsigned short Bs[256 * 64];
  const int t = threadIdx.x;
  const int wave = t >> 6, lane = t & 63;
  const int m0 = blockIdx.x * 64;
  const int wn = wave * 64;
  const int l8 = lane >> 3;
  const int lbs = (lane & 7) ^ l8;
  const int row_c = lane & 15, quad = lane >> 4;

  f32x4_t acc[4][4];
#pragma unroll
  for (int i = 0; i < 4; i++)
#pragma unroll
    for (int j = 0; j < 4; j++) acc[i][j] = (f32x4_t){0.f, 0.f, 0.f, 0.f};

  for (int k0 = 0; k0 < DIN; k0 += 64) {
#pragma unroll
    for (int j = 0; j < 8; j++) {
      int chunk = wave * 8 + j;  // 32 chunks x 8 rows = 256 B-rows
      int row = chunk * 8 + l8;
      const unsigned short* g = Bt + (size_t)row * DIN + k0 + lbs * 8;
      __builtin_amdgcn_global_load_lds(
          (const __attribute__((address_space(1))) unsigned int*)g,
          (__attribute__((address_space(3))) unsigned int*)(Bs + chunk * 512), 16, 0, 0);
    }
#pragma unroll
    for (int i = 0; i < 2; i++) {
      int bid = i * 256 + t;  // 64 rows x 8 slots = 512 slots
      int row = bid >> 3, pb = bid & 7;
      int lb = pb ^ (row & 7);
      int gm = m0 + row;
      if (gm >= M) gm = M - 1;
      const float4* s = (const float4*)(A + (size_t)gm * DIN + k0 + lb * 8);
      float4 v0 = s[0], v1 = s[1];
      uint4 o;
      o.x = pk2(v0.x, v0.y);
      o.y = pk2(v0.z, v0.w);
      o.z = pk2(v1.x, v1.y);
      o.w = pk2(v1.z, v1.w);
      *(uint4*)(As + row * 64 + pb * 8) = o;
    }
    __syncthreads();
#pragma unroll
    for (int ki = 0; ki < 2; ki++) {
      bf16x8_t af[4], bfr[4];
      int kb = ki * 4 + quad;
#pragma unroll
      for (int i = 0; i < 4; i++) {
        int ar = i * 16 + row_c;
        af[i] = *(const bf16x8_t*)(As + ar * 64 + ((kb ^ (ar & 7)) * 8));
        int br = wn + i * 16 + row_c;
        bfr[i] = *(const bf16x8_t*)(Bs + br * 64 + ((kb ^ (br & 7)) * 8));
      }
#pragma unroll
      for (int i = 0; i < 4; i++)
#pragma unroll
        for (int j = 0; j < 4; j++)
          acc[i][j] = __builtin_amdgcn_mfma_f32_16x16x32_bf16(af[i], bfr[j], acc[i][j], 0, 0, 0);
    }
    __syncthreads();
  }
#pragma unroll
  for (int i = 0; i < 4; i++) {
#pragma unroll
    for (int j = 0; j < 4; j++) {
      int colv = wn + j * 16 + row_c;
#pragma unroll
      for (int r = 0; r < 4; r++) {
        int gm = m0 + i * 16 + quad * 4 + r;
        if (gm < M) C[(size_t)gm * D1 + colv] = f2bf(acc[i][j][r]);
      }
    }
  }
}

// per-column BN1 scale/shift from stats
__global__ void k_finalize1(const float* __restrict__ stats, const float* __restrict__ gamma,
                            const float* __restrict__ beta, float* __restrict__ sc1,
                            float* __restrict__ sh1) {
  int c = threadIdx.x;  // 256
  float mean = stats[c] * (1.0f / NN);
  float var = stats[D1 + c] * (1.0f / NN) - mean * mean;
  float sc = gamma[c] * rsqrtf(var + EPSV);
  sc1[c] = sc;
  sh1[c] = beta[c] - mean * sc;
}

// ---------- GEMM2: H2[M x 128] = relu(BN(A1))[M x 256] @ W2t[128 x 256]^T ----------
// BM=64 (782 blocks), 128 threads = 2 waves in 1x2 N-grid, 64x64 each.
__global__ __launch_bounds__(128) void k_gemm2(const unsigned short* __restrict__ A,
                                               const float* __restrict__ sc1,
                                               const float* __restrict__ sh1,
                                               const unsigned short* __restrict__ Bt,
                                               unsigned short* __restrict__ C, int M) {
  __shared__ unsigned short As[64 * 64];
  __shared__ unsigned short Bs[128 * 64];
  const int t = threadIdx.x;
  const int wave = t >> 6, lane = t & 63;
  const int m0 = blockIdx.x * 64;
  const int wn = wave * 64;
  const int l8 = lane >> 3;
  const int lbs = (lane & 7) ^ l8;
  const int row_c = lane & 15, quad = lane >> 4;

  f32x4_t acc[4][4];
#pragma unroll
  for (int i = 0; i < 4; i++)
#pragma unroll
    for (int j = 0; j < 4; j++) acc[i][j] = (f32x4_t){0.f, 0.f, 0.f, 0.f};

  for (int k0 = 0; k0 < D1; k0 += 64) {
#pragma unroll
    for (int j = 0; j < 8; j++) {
      int chunk = wave * 8 + j;  // 16 chunks x 8 rows = 128 B-rows
      int row = chunk * 8 + l8;
      const unsigned short* g = Bt + (size_t)row * D1 + k0 + lbs * 8;
      __builtin_amdgcn_global_load_lds(
          (const __attribute__((address_space(1))) unsigned int*)g,
          (__attribute__((address_space(3))) unsigned int*)(Bs + chunk * 512), 16, 0, 0);
    }
#pragma unroll
    for (int i = 0; i < 4; i++) {
      int bid = i * 128 + t;  // 64 rows x 8 slots = 512 slots
      int row = bid >> 3, pb = bid & 7;
      int lb = pb ^ (row & 7);
      int gm = m0 + row;
      if (gm >= M) gm = M - 1;
      int colb = k0 + lb * 8;
      uint4 raw = *(const uint4*)(A + (size_t)gm * D1 + colb);
      float4 scA = *(const float4*)(sc1 + colb);
      float4 scB = *(const float4*)(sc1 + colb + 4);
      float4 shA = *(const float4*)(sh1 + colb);
      float4 shB = *(const float4*)(sh1 + colb + 4);
      float f0 = fmaxf(fmaf(bf2f((unsigned short)(raw.x & 0xffff)), scA.x, shA.x), 0.f);
      float f1 = fmaxf(fmaf(bf2f((unsigned short)(raw.x >> 16)),    scA.y, shA.y), 0.f);
      float f2 = fmaxf(fmaf(bf2f((unsigned short)(raw.y & 0xffff)), scA.z, shA.z), 0.f);
      float f3 = fmaxf(fmaf(bf2f((unsigned short)(raw.y >> 16)),    scA.w, shA.w), 0.f);
      float f4 = fmaxf(fmaf(bf2f((unsigned short)(raw.z & 0xffff)), scB.x, shB.x), 0.f);
      float f5 = fmaxf(fmaf(bf2f((unsigned short)(raw.z >> 16)),    scB.y, shB.y), 0.f);
      float f6 = fmaxf(fmaf(bf2f((unsigned short)(raw.w & 0xffff)), scB.z, shB.z), 0.f);
      float f7 = fmaxf(fmaf(bf2f((unsigned short)(raw.w >> 16)),    scB.w, shB.w), 0.f);
      uint4 o;
      o.x = pk2(f0, f1);
      o.y = pk2(f2, f3);
      o.z = pk2(f4, f5);
      o.w = pk2(f6, f7);
      *(uint4*)(As + row * 64 + pb * 8) = o;
    }
    __syncthreads();
#pragma unroll
    for (int ki = 0; ki < 2; ki++) {
      bf16x8_t af[4], bfr[4];
      int kb = ki * 4 + quad;
#pragma unroll
      for (int i = 0; i < 4; i++) {
        int ar = i * 16 + row_c;
        af[i] = *(const bf16x8_t*)(As + ar * 64 + ((kb ^ (ar & 7)) * 8));
        int br = wn + i * 16 + row_c;
        bfr[i] = *(const bf16x8_t*)(Bs + br * 64 + ((kb ^ (br & 7)) * 8));
      }
#pragma unroll
      for (int i = 0; i < 4; i++)
#pragma unroll
        for (int j = 0; j < 4; j++)
          acc[i][j] = __builtin_amdgcn_mfma_f32_16x16x32_bf16(af[i], bfr[j], acc[i][j], 0, 0, 0);
    }
    __syncthreads();
  }
#pragma unroll
  for (int i = 0; i < 4; i++) {
#pragma unroll
    for (int j = 0; j < 4; j++) {
      int colv = wn + j * 16 + row_c;  // < 128 = D2
#pragma unroll
      for (int r = 0; r < 4; r++) {
        int gm = m0 + i * 16 + quad * 4 + r;
        if (gm < M) C[(size_t)gm * D2 + colv] = f2bf(acc[i][j][r]);
      }
    }
  }
}

// ---------- CSR aggregation ----------
// R13: agg1 split into two 128-column passes (half = 0/1). Per pass the
// effective gather array is 12.8MB (3.2x per-XCD L2 oversubscription vs 6.4x)
// -> higher L2 hit at identical L2-level bytes. Structure otherwise identical
// to R7: per 64-edge block one coalesced col load + one dis gather, readlane
// broadcast to SGPRs, 8-deep row gathers (256B each).
__global__ __launch_bounds__(256) void k_agg1h(const unsigned short* __restrict__ H,
                                               const int* __restrict__ row_ptr,
                                               const int* __restrict__ col,
                                               const float* __restrict__ dis,
                                               const float* __restrict__ bias,
                                               unsigned short* __restrict__ OUT,
                                               int half) {
  int n = blockIdx.x * 4 + (threadIdx.x >> 6);
  int lane = threadIdx.x & 63;
  if (n >= NN) return;
  const unsigned short* Hh = H + half * 128;   // column-half base
  float dn = dis[n];
  ushort2 v = ((const ushort2*)(Hh + (size_t)n * D1))[lane];
  float wsf = dn * dn;
  float a0 = wsf * bf2f(v.x), a1 = wsf * bf2f(v.y);
  int e = row_ptr[n], e1 = row_ptr[n + 1];
  while (e < e1) {
    int cnt = e1 - e;
    if (cnt > 64) cnt = 64;
    int li = (lane < cnt) ? lane : (cnt - 1);
    int cv = col[e + li];                 // 64 edges' src ids, one load
    float dwv = dis[cv] * dn;             // 64 edges' weights, one gather
    int dwu = __float_as_int(dwv);
    int b = 0;
    for (; b + 8 <= cnt; b += 8) {
      int s[8];
      float w[8];
      ushort2 u[8];
#pragma unroll
      for (int k = 0; k < 8; k++) {
        s[k] = __builtin_amdgcn_readlane(cv, b + k);
        w[k] = __int_as_float(__builtin_amdgcn_readlane(dwu, b + k));
      }
#pragma unroll
      for (int k = 0; k < 8; k++)
        u[k] = ((const ushort2*)(Hh + (size_t)s[k] * D1))[lane];
#pragma unroll
      for (int k = 0; k < 8; k++) {
        a0 += w[k] * bf2f(u[k].x);
        a1 += w[k] * bf2f(u[k].y);
      }
    }
    for (; b < cnt; b++) {
      int sK = __builtin_amdgcn_readlane(cv, b);
      float wK = __int_as_float(__builtin_amdgcn_readlane(dwu, b));
      ushort2 uK = ((const ushort2*)(Hh + (size_t)sK * D1))[lane];
      a0 += wK * bf2f(uK.x);
      a1 += wK * bf2f(uK.y);
    }
    e += cnt;
  }
  int c = half * 128 + lane * 2;
  a0 += bias[c]; a1 += bias[c + 1];
  ushort2 o;
  o.x = f2bf(a0); o.y = f2bf(a1);
  ((ushort2*)(OUT + (size_t)n * D1 + half * 128))[lane] = o;
}

__global__ __launch_bounds__(256) void k_agg2(const unsigned short* __restrict__ H,
                                              const int* __restrict__ row_ptr,
                                              const int* __restrict__ col,
                                              const float* __restrict__ dis,
                                              const float* __restrict__ bias,
                                              float* __restrict__ OUT) {
  int n = blockIdx.x * 4 + (threadIdx.x >> 6);
  int lane = threadIdx.x & 63;
  if (n >= NN) return;
  float dn = dis[n];
  ushort2 v = ((const ushort2*)(H + (size_t)n * D2))[lane];
  float wsf = dn * dn;
  float a0 = wsf * bf2f(v.x), a1 = wsf * bf2f(v.y);
  int e = row_ptr[n], e1 = row_ptr[n + 1];
  while (e < e1) {
    int cnt = e1 - e;
    if (cnt > 64) cnt = 64;
    int li = (lane < cnt) ? lane : (cnt - 1);
    int cv = col[e + li];
    float dwv = dis[cv] * dn;
    int dwu = __float_as_int(dwv);
    int b = 0;
    for (; b + 8 <= cnt; b += 8) {
      int s[8];
      float w[8];
      ushort2 u[8];
#pragma unroll
      for (int k = 0; k < 8; k++) {
        s[k] = __builtin_amdgcn_readlane(cv, b + k);
        w[k] = __int_as_float(__builtin_amdgcn_readlane(dwu, b + k));
      }
#pragma unroll
      for (int k = 0; k < 8; k++)
        u[k] = ((const ushort2*)(H + (size_t)s[k] * D2))[lane];
#pragma unroll
      for (int k = 0; k < 8; k++) {
        a0 += w[k] * bf2f(u[k].x);
        a1 += w[k] * bf2f(u[k].y);
      }
    }
    for (; b < cnt; b++) {
      int sK = __builtin_amdgcn_readlane(cv, b);
      float wK = __int_as_float(__builtin_amdgcn_readlane(dwu, b));
      ushort2 uK = ((const ushort2*)(H + (size_t)sK * D2))[lane];
      a0 += wK * bf2f(uK.x);
      a1 += wK * bf2f(uK.y);
    }
    e += cnt;
  }
  int c = lane * 2;
  a0 += bias[c]; a1 += bias[c + 1];
  ((float2*)(OUT + (size_t)n * D2))[lane] = make_float2(a0, a1);
}

// ---------- BatchNorm stats ----------
__global__ void k_stats1(const unsigned short* __restrict__ X, float* __restrict__ stats) {
  int t = threadIdx.x;  // column 0..255
  int r0 = blockIdx.x * 64;
  int r1 = (r0 + 64 < NN) ? r0 + 64 : NN;
  float s = 0.f, q = 0.f;
  for (int r = r0; r < r1; r++) {
    float v = bf2f(X[(size_t)r * D1 + t]);
    s += v;
    q += v * v;
  }
  atomicAdd(&stats[t], s);
  atomicAdd(&stats[D1 + t], q);
}

__global__ void k_stats2(const float* __restrict__ X, float* __restrict__ stats) {
  int t = threadIdx.x;  // column 0..127
  int r0 = blockIdx.x * 128;
  int r1 = (r0 + 128 < NN) ? r0 + 128 : NN;
  float s = 0.f, q = 0.f;
  for (int r = r0; r < r1; r++) {
    float v = X[(size_t)r * D2 + t];
    s += v;
    q += v * v;
  }
  atomicAdd(&stats[t], s);
  atomicAdd(&stats[D2 + t], q);
}

__global__ void k_apply2(float* __restrict__ X, const float* __restrict__ stats,
                         const float* __restrict__ gamma, const float* __restrict__ beta) {
  int i = blockIdx.x * blockDim.x + threadIdx.x;
  int c = i & (D2 - 1);
  float mean = stats[c] * (1.0f / NN);
  float var = stats[D2 + c] * (1.0f / NN) - mean * mean;
  float sc = gamma[c] * rsqrtf(var + EPSV);
  X[i] = (X[i] - mean) * sc + beta[c];
}

extern "C" void kernel_launch(void* const* d_in, const int* in_sizes, int n_in,
                              void* d_out, int out_size, void* d_ws, size_t ws_size,
                              hipStream_t stream) {
  const float* x  = (const float*)d_in[0];
  const int* ei   = (const int*)d_in[1];  // [2, NE], int32
  const int* srcv = ei;
  const int* dstv = ei + NE;
  const float* W1  = (const float*)d_in[2];
  const float* b1  = (const float*)d_in[3];
  const float* g1  = (const float*)d_in[4];
  const float* be1 = (const float*)d_in[5];
  const float* W2  = (const float*)d_in[6];
  const float* b2  = (const float*)d_in[7];
  const float* g2  = (const float*)d_in[8];
  const float* be2 = (const float*)d_in[9];
  float* out = (float*)d_out;

  char* ws = (char*)d_ws;
  size_t off = 0;
  auto alloc = [&](size_t bytes) {
    size_t cur = off;
    off = (off + bytes + 255) & ~(size_t)255;
    return cur;
  };
  int* row_ptr   = (int*)(ws + alloc((NN + 1) * 4));
  float* dis     = (float*)(ws + alloc(NN * 4));
  int* gcursor   = (int*)(ws + alloc(NDB * 4));
  int* ebase     = (int*)(ws + alloc((NDB + 1) * 4));
  float* stats   = (float*)(ws + alloc((D1 * 2 + D2 * 2) * 4));
  float* sc1     = (float*)(ws + alloc(D1 * 4));
  float* sh1     = (float*)(ws + alloc(D1 * 4));
  int* col       = (int*)(ws + alloc((size_t)NE * 4));
  unsigned short* H1  = (unsigned short*)(ws + alloc((size_t)NN * D1 * 2));
  unsigned short* A1  = (unsigned short*)(ws + alloc((size_t)NN * D1 * 2));
  unsigned short* H2  = (unsigned short*)(ws + alloc((size_t)NN * D2 * 2));
  unsigned short* W1t = (unsigned short*)(ws + alloc((size_t)DIN * D1 * 2));
  unsigned short* W2t = (unsigned short*)(ws + alloc((size_t)D1 * D2 * 2));
  float* stats2 = stats + D1 * 2;
  // part aliases H1 (dead until k_gemm1; 8.4 MB <= 25.6 MB)
  unsigned int* part = (unsigned int*)H1;

  // CSR build: partition -> bucket scan -> per-bucket counting sort
  k_zero<<<3, 256, 0, stream>>>(gcursor, stats);
  k_part<<<256, 256, 0, stream>>>(srcv, dstv, gcursor, part);
  k_bscan<<<1, NDB, 0, stream>>>(gcursor, ebase);
  k_build<<<NDB, 256, 0, stream>>>(part, gcursor, ebase, row_ptr, dis, col);

  // weight transpose + bf16 convert
  k_prep_w<<<(DIN * D1 + D1 * D2) / 256, 256, 0, stream>>>(W1, W2, W1t, W2t);

  const int mb = (NN + 63) / 64;  // 782

  // conv1
  k_gemm1<<<mb, 256, 0, stream>>>(x, W1t, H1, NN);
  k_agg1h<<<(NN + 3) / 4, 256, 0, stream>>>(H1, row_ptr, col, dis, b1, A1, 0);
  k_agg1h<<<(NN + 3) / 4, 256, 0, stream>>>(H1, row_ptr, col, dis, b1, A1, 1);
  k_stats1<<<(NN + 63) / 64, 256, 0, stream>>>(A1, stats);
  k_finalize1<<<1, 256, 0, stream>>>(stats, g1, be1, sc1, sh1);

  // conv2
  k_gemm2<<<mb, 128, 0, stream>>>(A1, sc1, sh1, W2t, H2, NN);
  k_agg2<<<(NN + 3) / 4, 256, 0, stream>>>(H2, row_ptr, col, dis, b2, out);
  k_stats2<<<(NN + 127) / 128, 128, 0, stream>>>(out, stats2);
  k_apply2<<<NN * D2 / 256, 256, 0, stream>>>(out, stats2, g2, be2);
}

// Round 8
// 494.090 us; speedup vs baseline: 1.3543x; 1.0376x over previous
//
#include <hip/hip_runtime.h>
#include <hip/hip_bf16.h>

// GCN encoder: conv1(512->256) -> BN -> ReLU -> conv2(256->128) -> BN
// R14: makespan round. R13 showed no kernel >59us (top-5 all harness fills)
// -> attack serialization, not per-kernel FLOPs. (1) k_build merged with
// k_gemm1 (910 blocks, blockIdx-range dispatch, 40KB LDS union): CSR sort is
// memory/LDS-bound, gemm1 is MFMA-bound, zero data overlap once part[] stops
// aliasing H1 (own 8.4MB region). (2) k_part merged with k_prep_w (896
// blocks). (3) k_zero replaced by one 3.6KB hipMemsetAsync (gcursor+stats
// adjacent). 15 -> 12 dispatches. All inner bodies byte-identical to R13
// (R11 lesson: only remap indices, never touch staging logic).
// Kept from R13: agg1 column-split (two 128-col passes), R7 streaming agg2,
// BM=64 GEMMs, BN1+ReLU fused in gemm2 staging.

#define NN 50000
#define NE 1600000
#define DIN 512
#define D1 256
#define D2 128
#define EPSV 1e-5f
#define NBUCK 16    // src buckets (agg L2 lockstep); 4 bits in packed word
#define BSZ 3125    // nodes per src bucket (16*3125 = 50000)
#define NDB 128     // dst buckets (CSR build)
#define NPB 391     // nodes per dst bucket (128*391 = 50048 >= NN)
#define CAP 16384   // part capacity per dst bucket (mean 12500, >30 sigma)

typedef __attribute__((ext_vector_type(8))) short bf16x8_t;
typedef __attribute__((ext_vector_type(4))) float f32x4_t;

__device__ __forceinline__ float bf2f(unsigned short u) {
  return __uint_as_float(((unsigned int)u) << 16);
}
__device__ __forceinline__ unsigned short f2bf(float f) {
  unsigned int u = __float_as_uint(f);
  u += 0x7fffu + ((u >> 16) & 1u);   // RNE
  return (unsigned short)(u >> 16);
}
__device__ __forceinline__ unsigned int pk2(float a, float b) {
  __hip_bfloat162 h = __float22bfloat162_rn(make_float2(a, b));
  union { __hip_bfloat162 h; unsigned int u; } c;
  c.h = h;
  return c.u;
}

// ---------- L1: edge partition (blocks 0..255) + weight prep (256..895) ----------
// part: packed word = src (16b) | dst_local (9b, <<16) | src_bucket (4b, <<25)
__global__ __launch_bounds__(256) void k_part_prep(const int* __restrict__ src,
                                                   const int* __restrict__ dst,
                                                   int* __restrict__ gcursor,
                                                   unsigned int* __restrict__ part,
                                                   const float* __restrict__ W1,
                                                   const float* __restrict__ W2,
                                                   unsigned short* __restrict__ W1t,
                                                   unsigned short* __restrict__ W2t) {
  __shared__ int hist[NDB];
  __shared__ int curs[NDB];
  const int t = threadIdx.x;
  if (blockIdx.x < 256) {
    const int EB = NE / 256;  // 6250 edges per block
    const int e0 = blockIdx.x * EB;
    if (t < NDB) hist[t] = 0;
    __syncthreads();
    for (int i = t; i < EB; i += 256) {
      int d = dst[e0 + i];
      atomicAdd(&hist[d / NPB], 1);
    }
    __syncthreads();
    if (t < NDB) {
      int c = hist[t];
      curs[t] = (c > 0) ? atomicAdd(&gcursor[t], c) : 0;
    }
    __syncthreads();
    for (int i = t; i < EB; i += 256) {
      int s = src[e0 + i];
      int d = dst[e0 + i];
      int b = d / NPB;
      int dl = d - b * NPB;
      int sb = (unsigned)s / BSZ;
      unsigned int w = (unsigned)s | ((unsigned)dl << 16) | ((unsigned)sb << 25);
      int pos = atomicAdd(&curs[b], 1);
      if (pos < CAP) part[(size_t)b * CAP + pos] = w;
    }
  } else {
    int i = (blockIdx.x - 256) * 256 + t;
    if (i < DIN * D1) {  // W1t[n*DIN + k] = W1[k*D1 + n]
      int n = i / DIN, k = i - n * DIN;
      W1t[i] = f2bf(W1[(size_t)k * D1 + n]);
    } else {
      int j = i - DIN * D1;  // W2t[n*D1 + k] = W2[k*D2 + n]
      int n = j / D1, k = j - n * D1;
      W2t[j] = f2bf(W2[(size_t)k * D2 + n]);
    }
  }
}

// exclusive prefix over 128 bucket totals -> ebase
__global__ void k_bscan(const int* __restrict__ gcursor, int* __restrict__ ebase) {
  __shared__ int s[NDB];
  int t = threadIdx.x;  // blockDim = 128
  int v = gcursor[t];
  s[t] = v;
  __syncthreads();
  for (int off = 1; off < NDB; off <<= 1) {
    int a = (t >= off) ? s[t - off] : 0;
    __syncthreads();
    s[t] += a;
    __syncthreads();
  }
  ebase[t] = s[t] - v;
  if (t == NDB - 1) ebase[NDB] = s[t];
}

// ---------- L3: CSR counting sort (blocks 0..127) + GEMM1 (128..909) ----------
// build: per dst-bucket LDS counting sort by (node_local, src_bucket); emits
// row_ptr, dis, col. gemm1: H1[M x 256] = x[M x 512] @ W1t^T, BM=64.
// 40KB LDS union: build uses cnt[6256]+tsum[256] (26KB); gemm1 As 8KB + Bs 32KB.
__global__ __launch_bounds__(256) void k_build_gemm1(const unsigned int* __restrict__ part,
                                                     const int* __restrict__ gcursor,
                                                     const int* __restrict__ ebase,
                                                     int* __restrict__ row_ptr,
                                                     float* __restrict__ dis,
                                                     int* __restrict__ col,
                                                     const float* __restrict__ A,
                                                     const unsigned short* __restrict__ Bt,
                                                     unsigned short* __restrict__ C, int M) {
  __shared__ __align__(16) char smem[40960];
  const int t = threadIdx.x;
  if (blockIdx.x < NDB) {
    // ---- CSR build ----
    const int NC = NPB * NBUCK;  // 6256 counters
    int* cnt = (int*)smem;                 // 25024 B
    int* tsum = (int*)(smem + 25024);      // 1024 B
    const int b = blockIdx.x;
    int m = gcursor[b];
    if (m > CAP) m = CAP;
    const int base = ebase[b];
    const unsigned int* my = part + (size_t)b * CAP;
    for (int i = t; i < NC; i += 256) cnt[i] = 0;
    __syncthreads();
    for (int i = t; i < m; i += 256) {
      unsigned int w = my[i];
      atomicAdd(&cnt[((w >> 16) & 0x1ff) * NBUCK + (w >> 25)], 1);
    }
    __syncthreads();
    // exclusive scan of cnt[0..NC)
    const int CHK = (NC + 255) / 256;  // 25
    int i0 = t * CHK;
    int sum = 0;
    for (int i = 0; i < CHK; i++) {
      int idx = i0 + i;
      if (idx < NC) sum += cnt[idx];
    }
    tsum[t] = sum;
    __syncthreads();
    for (int off = 1; off < 256; off <<= 1) {
      int a = (t >= off) ? tsum[t - off] : 0;
      __syncthreads();
      tsum[t] += a;
      __syncthreads();
    }
    int run = tsum[t] - sum;
    for (int i = 0; i < CHK; i++) {
      int idx = i0 + i;
      if (idx < NC) {
        int c = cnt[idx];
        cnt[idx] = run;
        run += c;
      }
    }
    __syncthreads();
    // row_ptr / dis from scan values
    const int n0 = b * NPB;
    for (int dl = t; dl < NPB; dl += 256) {
      int n = n0 + dl;
      if (n < NN) {
        int st = cnt[dl * NBUCK];
        int en = (dl * NBUCK + NBUCK < NC) ? cnt[dl * NBUCK + NBUCK] : m;
        row_ptr[n] = base + st;
        dis[n] = rsqrtf((float)(en - st + 1));  // +1 self loop
      }
    }
    if (b == NDB - 1 && t == 0) row_ptr[NN] = base + m;
    __syncthreads();
    // scatter (cnt now serves as cursors); col segment [base, base+m) is dense
    for (int i = t; i < m; i += 256) {
      unsigned int w = my[i];
      int pos = atomicAdd(&cnt[((w >> 16) & 0x1ff) * NBUCK + (w >> 25)], 1);
      col[base + pos] = w & 0xffff;
    }
  } else {
    // ---- GEMM1, BM=64: 4 waves in 1x4 N-grid, 64Mx64N each ----
    unsigned short* As = (unsigned short*)smem;           // 64*64*2 = 8192 B
    unsigned short* Bs = (unsigned short*)(smem + 8192);  // 256*64*2 = 32768 B
    const int wave = t >> 6, lane = t & 63;
    const int m0 = (blockIdx.x - NDB) * 64;
    const int wn = wave * 64;
    const int l8 = lane >> 3;
    const int lbs = (lane & 7) ^ l8;
    const int row_c = lane & 15, quad = lane >> 4;

    f32x4_t acc[4][4];
#pragma unroll
    for (int i = 0; i < 4; i++)
#pragma unroll
      for (int j = 0; j < 4; j++) acc[i][j] = (f32x4_t){0.f, 0.f, 0.f, 0.f};

    for (int k0 = 0; k0 < DIN; k0 += 64) {
#pragma unroll
      for (int j = 0; j < 8; j++) {
        int chunk = wave * 8 + j;  // 32 chunks x 8 rows = 256 B-rows
        int row = chunk * 8 + l8;
        const unsigned short* g = Bt + (size_t)row * DIN + k0 + lbs * 8;
        __builtin_amdgcn_global_load_lds(
            (const __attribute__((address_space(1))) unsigned int*)g,
            (__attribute__((address_space(3))) unsigned int*)(Bs + chunk * 512), 16, 0, 0);
      }
#pragma unroll
      for (int i = 0; i < 2; i++) {
        int bid = i * 256 + t;  // 64 rows x 8 slots = 512 slots
        int row = bid >> 3, pb = bid & 7;
        int lb = pb ^ (row & 7);
        int gm = m0 + row;
        if (gm >= M) gm = M - 1;
        const float4* s = (const float4*)(A + (size_t)gm * DIN + k0 + lb * 8);
        float4 v0 = s[0], v1 = s[1];
        uint4 o;
        o.x = pk2(v0.x, v0.y);
        o.y = pk2(v0.z, v0.w);
        o.z = pk2(v1.x, v1.y);
        o.w = pk2(v1.z, v1.w);
        *(uint4*)(As + row * 64 + pb * 8) = o;
      }
      __syncthreads();
#pragma unroll
      for (int ki = 0; ki < 2; ki++) {
        bf16x8_t af[4], bfr[4];
        int kb = ki * 4 + quad;
#pragma unroll
        for (int i = 0; i < 4; i++) {
          int ar = i * 16 + row_c;
          af[i] = *(const bf16x8_t*)(As + ar * 64 + ((kb ^ (ar & 7)) * 8));
          int br = wn + i * 16 + row_c;
          bfr[i] = *(const bf16x8_t*)(Bs + br * 64 + ((kb ^ (br & 7)) * 8));
        }
#pragma unroll
        for (int i = 0; i < 4; i++)
#pragma unroll
          for (int j = 0; j < 4; j++)
            acc[i][j] = __builtin_amdgcn_mfma_f32_16x16x32_bf16(af[i], bfr[j], acc[i][j], 0, 0, 0);
      }
      __syncthreads();
    }
#pragma unroll
    for (int i = 0; i < 4; i++) {
#pragma unroll
      for (int j = 0; j < 4; j++) {
        int colv = wn + j * 16 + row_c;
#pragma unroll
        for (int r = 0; r < 4; r++) {
          int gm = m0 + i * 16 + quad * 4 + r;
          if (gm < M) C[(size_t)gm * D1 + colv] = f2bf(acc[i][j][r]);
        }
      }
    }
  }
}

// per-column BN1 scale/shift from stats
__global__ void k_finalize1(const float* __restrict__ stats, const float* __restrict__ gamma,
                            const float* __restrict__ beta, float* __restrict__ sc1,
                            float* __restrict__ sh1) {
  int c = threadIdx.x;  // 256
  float mean = stats[c] * (1.0f / NN);
  float var = stats[D1 + c] * (1.0f / NN) - mean * mean;
  float sc = gamma[c] * rsqrtf(var + EPSV);
  sc1[c] = sc;
  sh1[c] = beta[c] - mean * sc;
}

// ---------- GEMM2: H2[M x 128] = relu(BN(A1))[M x 256] @ W2t[128 x 256]^T ----------
// BM=64 (782 blocks), 128 threads = 2 waves in 1x2 N-grid, 64x64 each.
__global__ __launch_bounds__(128) void k_gemm2(const unsigned short* __restrict__ A,
                                               const float* __restrict__ sc1,
                                               const float* __restrict__ sh1,
                                               const unsigned short* __restrict__ Bt,
                                               unsigned short* __restrict__ C, int M) {
  __shared__ unsigned short As[64 * 64];
  __shared__ unsigned short Bs[128 * 64];
  const int t = threadIdx.x;
  const int wave = t >> 6, lane = t & 63;
  const int m0 = blockIdx.x * 64;
  const int wn = wave * 64;
  const int l8 = lane >> 3;
  const int lbs = (lane & 7) ^ l8;
  const int row_c = lane & 15, quad = lane >> 4;

  f32x4_t acc[4][4];
#pragma unroll
  for (int i = 0; i < 4; i++)
#pragma unroll
    for (int j = 0; j < 4; j++) acc[i][j] = (f32x4_t){0.f, 0.f, 0.f, 0.f};

  for (int k0 = 0; k0 < D1; k0 += 64) {
#pragma unroll
    for (int j = 0; j < 8; j++) {
      int chunk = wave * 8 + j;  // 16 chunks x 8 rows = 128 B-rows
      int row = chunk * 8 + l8;
      const unsigned short* g = Bt + (size_t)row * D1 + k0 + lbs * 8;
      __builtin_amdgcn_global_load_lds(
          (const __attribute__((address_space(1))) unsigned int*)g,
          (__attribute__((address_space(3))) unsigned int*)(Bs + chunk * 512), 16, 0, 0);
    }
#pragma unroll
    for (int i = 0; i < 4; i++) {
      int bid = i * 128 + t;  // 64 rows x 8 slots = 512 slots
      int row = bid >> 3, pb = bid & 7;
      int lb = pb ^ (row & 7);
      int gm = m0 + row;
      if (gm >= M) gm = M - 1;
      int colb = k0 + lb * 8;
      uint4 raw = *(const uint4*)(A + (size_t)gm * D1 + colb);
      float4 scA = *(const float4*)(sc1 + colb);
      float4 scB = *(const float4*)(sc1 + colb + 4);
      float4 shA = *(const float4*)(sh1 + colb);
      float4 shB = *(const float4*)(sh1 + colb + 4);
      float f0 = fmaxf(fmaf(bf2f((unsigned short)(raw.x & 0xffff)), scA.x, shA.x), 0.f);
      float f1 = fmaxf(fmaf(bf2f((unsigned short)(raw.x >> 16)),    scA.y, shA.y), 0.f);
      float f2 = fmaxf(fmaf(bf2f((unsigned short)(raw.y & 0xffff)), scA.z, shA.z), 0.f);
      float f3 = fmaxf(fmaf(bf2f((unsigned short)(raw.y >> 16)),    scA.w, shA.w), 0.f);
      float f4 = fmaxf(fmaf(bf2f((unsigned short)(raw.z & 0xffff)), scB.x, shB.x), 0.f);
      float f5 = fmaxf(fmaf(bf2f((unsigned short)(raw.z >> 16)),    scB.y, shB.y), 0.f);
      float f6 = fmaxf(fmaf(bf2f((unsigned short)(raw.w & 0xffff)), scB.z, shB.z), 0.f);
      float f7 = fmaxf(fmaf(bf2f((unsigned short)(raw.w >> 16)),    scB.w, shB.w), 0.f);
      uint4 o;
      o.x = pk2(f0, f1);
      o.y = pk2(f2, f3);
      o.z = pk2(f4, f5);
      o.w = pk2(f6, f7);
      *(uint4*)(As + row * 64 + pb * 8) = o;
    }
    __syncthreads();
#pragma unroll
    for (int ki = 0; ki < 2; ki++) {
      bf16x8_t af[4], bfr[4];
      int kb = ki * 4 + quad;
#pragma unroll
      for (int i = 0; i < 4; i++) {
        int ar = i * 16 + row_c;
        af[i] = *(const bf16x8_t*)(As + ar * 64 + ((kb ^ (ar & 7)) * 8));
        int br = wn + i * 16 + row_c;
        bfr[i] = *(const bf16x8_t*)(Bs + br * 64 + ((kb ^ (br & 7)) * 8));
      }
#pragma unroll
      for (int i = 0; i < 4; i++)
#pragma unroll
        for (int j = 0; j < 4; j++)
          acc[i][j] = __builtin_amdgcn_mfma_f32_16x16x32_bf16(af[i], bfr[j], acc[i][j], 0, 0, 0);
    }
    __syncthreads();
  }
#pragma unroll
  for (int i = 0; i < 4; i++) {
#pragma unroll
    for (int j = 0; j < 4; j++) {
      int colv = wn + j * 16 + row_c;  // < 128 = D2
#pragma unroll
      for (int r = 0; r < 4; r++) {
        int gm = m0 + i * 16 + quad * 4 + r;
        if (gm < M) C[(size_t)gm * D2 + colv] = f2bf(acc[i][j][r]);
      }
    }
  }
}

// ---------- CSR aggregation ----------
// agg1 split into two 128-column passes (half = 0/1): per-pass working set
// 12.8MB (3.2x per-XCD L2 oversubscription). Per 64-edge block: one coalesced
// col load + one dis gather, readlane broadcast to SGPRs, 8-deep row gathers.
__global__ __launch_bounds__(256) void k_agg1h(const unsigned short* __restrict__ H,
                                               const int* __restrict__ row_ptr,
                                               const int* __restrict__ col,
                                               const float* __restrict__ dis,
                                               const float* __restrict__ bias,
                                               unsigned short* __restrict__ OUT,
                                               int half) {
  int n = blockIdx.x * 4 + (threadIdx.x >> 6);
  int lane = threadIdx.x & 63;
  if (n >= NN) return;
  const unsigned short* Hh = H + half * 128;   // column-half base
  float dn = dis[n];
  ushort2 v = ((const ushort2*)(Hh + (size_t)n * D1))[lane];
  float wsf = dn * dn;
  float a0 = wsf * bf2f(v.x), a1 = wsf * bf2f(v.y);
  int e = row_ptr[n], e1 = row_ptr[n + 1];
  while (e < e1) {
    int cnt = e1 - e;
    if (cnt > 64) cnt = 64;
    int li = (lane < cnt) ? lane : (cnt - 1);
    int cv = col[e + li];                 // 64 edges' src ids, one load
    float dwv = dis[cv] * dn;             // 64 edges' weights, one gather
    int dwu = __float_as_int(dwv);
    int b = 0;
    for (; b + 8 <= cnt; b += 8) {
      int s[8];
      float w[8];
      ushort2 u[8];
#pragma unroll
      for (int k = 0; k < 8; k++) {
        s[k] = __builtin_amdgcn_readlane(cv, b + k);
        w[k] = __int_as_float(__builtin_amdgcn_readlane(dwu, b + k));
      }
#pragma unroll
      for (int k = 0; k < 8; k++)
        u[k] = ((const ushort2*)(Hh + (size_t)s[k] * D1))[lane];
#pragma unroll
      for (int k = 0; k < 8; k++) {
        a0 += w[k] * bf2f(u[k].x);
        a1 += w[k] * bf2f(u[k].y);
      }
    }
    for (; b < cnt; b++) {
      int sK = __builtin_amdgcn_readlane(cv, b);
      float wK = __int_as_float(__builtin_amdgcn_readlane(dwu, b));
      ushort2 uK = ((const ushort2*)(Hh + (size_t)sK * D1))[lane];
      a0 += wK * bf2f(uK.x);
      a1 += wK * bf2f(uK.y);
    }
    e += cnt;
  }
  int c = half * 128 + lane * 2;
  a0 += bias[c]; a1 += bias[c + 1];
  ushort2 o;
  o.x = f2bf(a0); o.y = f2bf(a1);
  ((ushort2*)(OUT + (size_t)n * D1 + half * 128))[lane] = o;
}

__global__ __launch_bounds__(256) void k_agg2(const unsigned short* __restrict__ H,
                                              const int* __restrict__ row_ptr,
                                              const int* __restrict__ col,
                                              const float* __restrict__ dis,
                                              const float* __restrict__ bias,
                                              float* __restrict__ OUT) {
  int n = blockIdx.x * 4 + (threadIdx.x >> 6);
  int lane = threadIdx.x & 63;
  if (n >= NN) return;
  float dn = dis[n];
  ushort2 v = ((const ushort2*)(H + (size_t)n * D2))[lane];
  float wsf = dn * dn;
  float a0 = wsf * bf2f(v.x), a1 = wsf * bf2f(v.y);
  int e = row_ptr[n], e1 = row_ptr[n + 1];
  while (e < e1) {
    int cnt = e1 - e;
    if (cnt > 64) cnt = 64;
    int li = (lane < cnt) ? lane : (cnt - 1);
    int cv = col[e + li];
    float dwv = dis[cv] * dn;
    int dwu = __float_as_int(dwv);
    int b = 0;
    for (; b + 8 <= cnt; b += 8) {
      int s[8];
      float w[8];
      ushort2 u[8];
#pragma unroll
      for (int k = 0; k < 8; k++) {
        s[k] = __builtin_amdgcn_readlane(cv, b + k);
        w[k] = __int_as_float(__builtin_amdgcn_readlane(dwu, b + k));
      }
#pragma unroll
      for (int k = 0; k < 8; k++)
        u[k] = ((const ushort2*)(H + (size_t)s[k] * D2))[lane];
#pragma unroll
      for (int k = 0; k < 8; k++) {
        a0 += w[k] * bf2f(u[k].x);
        a1 += w[k] * bf2f(u[k].y);
      }
    }
    for (; b < cnt; b++) {
      int sK = __builtin_amdgcn_readlane(cv, b);
      float wK = __int_as_float(__builtin_amdgcn_readlane(dwu, b));
      ushort2 uK = ((const ushort2*)(H + (size_t)sK * D2))[lane];
      a0 += wK * bf2f(uK.x);
      a1 += wK * bf2f(uK.y);
    }
    e += cnt;
  }
  int c = lane * 2;
  a0 += bias[c]; a1 += bias[c + 1];
  ((float2*)(OUT + (size_t)n * D2))[lane] = make_float2(a0, a1);
}

// ---------- BatchNorm stats ----------
__global__ void k_stats1(const unsigned short* __restrict__ X, float* __restrict__ stats) {
  int t = threadIdx.x;  // column 0..255
  int r0 = blockIdx.x * 64;
  int r1 = (r0 + 64 < NN) ? r0 + 64 : NN;
  float s = 0.f, q = 0.f;
  for (int r = r0; r < r1; r++) {
    float v = bf2f(X[(size_t)r * D1 + t]);
    s += v;
    q += v * v;
  }
  atomicAdd(&stats[t], s);
  atomicAdd(&stats[D1 + t], q);
}

__global__ void k_stats2(const float* __restrict__ X, float* __restrict__ stats) {
  int t = threadIdx.x;  // column 0..127
  int r0 = blockIdx.x * 128;
  int r1 = (r0 + 128 < NN) ? r0 + 128 : NN;
  float s = 0.f, q = 0.f;
  for (int r = r0; r < r1; r++) {
    float v = X[(size_t)r * D2 + t];
    s += v;
    q += v * v;
  }
  atomicAdd(&stats[t], s);
  atomicAdd(&stats[D2 + t], q);
}

__global__ void k_apply2(float* __restrict__ X, const float* __restrict__ stats,
                         const float* __restrict__ gamma, const float* __restrict__ beta) {
  int i = blockIdx.x * blockDim.x + threadIdx.x;
  int c = i & (D2 - 1);
  float mean = stats[c] * (1.0f / NN);
  float var = stats[D2 + c] * (1.0f / NN) - mean * mean;
  float sc = gamma[c] * rsqrtf(var + EPSV);
  X[i] = (X[i] - mean) * sc + beta[c];
}

extern "C" void kernel_launch(void* const* d_in, const int* in_sizes, int n_in,
                              void* d_out, int out_size, void* d_ws, size_t ws_size,
                              hipStream_t stream) {
  const float* x  = (const float*)d_in[0];
  const int* ei   = (const int*)d_in[1];  // [2, NE], int32
  const int* srcv = ei;
  const int* dstv = ei + NE;
  const float* W1  = (const float*)d_in[2];
  const float* b1  = (const float*)d_in[3];
  const float* g1  = (const float*)d_in[4];
  const float* be1 = (const float*)d_in[5];
  const float* W2  = (const float*)d_in[6];
  const float* b2  = (const float*)d_in[7];
  const float* g2  = (const float*)d_in[8];
  const float* be2 = (const float*)d_in[9];
  float* out = (float*)d_out;

  char* ws = (char*)d_ws;
  size_t off = 0;
  auto alloc = [&](size_t bytes) {
    size_t cur = off;
    off = (off + bytes + 255) & ~(size_t)255;
    return cur;
  };
  // gcursor + stats adjacent -> one memset (512 + 3072 bytes)
  int* gcursor   = (int*)(ws + alloc(NDB * 4));                  // 512 B padded
  float* stats   = (float*)(ws + alloc((D1 * 2 + D2 * 2) * 4));  // 3072 B
  int* row_ptr   = (int*)(ws + alloc((NN + 1) * 4));
  float* dis     = (float*)(ws + alloc(NN * 4));
  int* ebase     = (int*)(ws + alloc((NDB + 1) * 4));
  float* sc1     = (float*)(ws + alloc(D1 * 4));
  float* sh1     = (float*)(ws + alloc(D1 * 4));
  int* col       = (int*)(ws + alloc((size_t)NE * 4));
  unsigned int* part = (unsigned int*)(ws + alloc((size_t)NDB * CAP * 4));  // own region (no H1 alias)
  unsigned short* H1  = (unsigned short*)(ws + alloc((size_t)NN * D1 * 2));
  unsigned short* A1  = (unsigned short*)(ws + alloc((size_t)NN * D1 * 2));
  unsigned short* H2  = (unsigned short*)(ws + alloc((size_t)NN * D2 * 2));
  unsigned short* W1t = (unsigned short*)(ws + alloc((size_t)DIN * D1 * 2));
  unsigned short* W2t = (unsigned short*)(ws + alloc((size_t)D1 * D2 * 2));
  float* stats2 = stats + D1 * 2;

  // zero gcursor + stats (adjacent, 3584 B)
  hipMemsetAsync(gcursor, 0, NDB * 4 + (D1 * 2 + D2 * 2) * 4, stream);

  // L1: edge partition || weight prep
  k_part_prep<<<256 + 640, 256, 0, stream>>>(srcv, dstv, gcursor, part, W1, W2, W1t, W2t);
  k_bscan<<<1, NDB, 0, stream>>>(gcursor, ebase);

  const int mb = (NN + 63) / 64;  // 782

  // L3: CSR counting sort || GEMM1 (independent once part != H1)
  k_build_gemm1<<<NDB + mb, 256, 0, stream>>>(part, gcursor, ebase, row_ptr, dis, col,
                                              x, W1t, H1, NN);

  // conv1 aggregation (two column halves) + BN1 stats
  k_agg1h<<<(NN + 3) / 4, 256, 0, stream>>>(H1, row_ptr, col, dis, b1, A1, 0);
  k_agg1h<<<(NN + 3) / 4, 256, 0, stream>>>(H1, row_ptr, col, dis, b1, A1, 1);
  k_stats1<<<(NN + 63) / 64, 256, 0, stream>>>(A1, stats);
  k_finalize1<<<1, 256, 0, stream>>>(stats, g1, be1, sc1, sh1);

  // conv2
  k_gemm2<<<mb, 128, 0, stream>>>(A1, sc1, sh1, W2t, H2, NN);
  k_agg2<<<(NN + 3) / 4, 256, 0, stream>>>(H2, row_ptr, col, dis, b2, out);
  k_stats2<<<(NN + 127) / 128, 128, 0, stream>>>(out, stats2);
  k_apply2<<<NN * D2 / 256, 256, 0, stream>>>(out, stats2, g2, be2);
}